// Round 1
// baseline (864.533 us; speedup 1.0000x reference)
//
#include <hip/hip_runtime.h>
#include <stdint.h>

typedef __attribute__((ext_vector_type(8))) short short8;
typedef __attribute__((ext_vector_type(4))) float f32x4;

#define DIMC 768
#define NTOK 32768
#define NPB 4096
#define HEADS 8
#define DH 96

__device__ __forceinline__ ushort f2bf(float f) {
    union { float f; uint32_t u; } c; c.f = f;
    uint32_t u = c.u;
    u += 0x7fffu + ((u >> 16) & 1u);
    return (ushort)(u >> 16);
}
__device__ __forceinline__ float bf2f(ushort h) {
    union { uint32_t u; float f; } c; c.u = ((uint32_t)h) << 16;
    return c.f;
}

// ---------------- weight fp32 -> bf16 ----------------
__global__ __launch_bounds__(256) void cvtw_kernel(
    const float* __restrict__ qw, const float* __restrict__ pw,
    ushort* __restrict__ qwb, ushort* __restrict__ pwb) {
    int i = blockIdx.x * 256 + threadIdx.x;
    if (i < 3 * DIMC * DIMC) qwb[i] = f2bf(qw[i]);
    if (i < DIMC * DIMC) pwb[i] = f2bf(pw[i]);
}

// ---------------- LayerNorm stats (mean, rstd) per token ----------------
__global__ __launch_bounds__(256) void ln_stats_kernel(
    const float* __restrict__ x, float2* __restrict__ stats) {
    int t = blockIdx.x;
    int tid = threadIdx.x;
    const float* xr = x + (size_t)t * DIMC;
    float v0 = xr[tid], v1 = xr[tid + 256], v2 = xr[tid + 512];
    float s = v0 + v1 + v2;
    float s2 = v0 * v0 + v1 * v1 + v2 * v2;
#pragma unroll
    for (int off = 32; off > 0; off >>= 1) {
        s  += __shfl_down(s, off);
        s2 += __shfl_down(s2, off);
    }
    __shared__ float rs[4], rs2[4];
    int wid = tid >> 6, lane = tid & 63;
    if (lane == 0) { rs[wid] = s; rs2[wid] = s2; }
    __syncthreads();
    if (tid == 0) {
        float a = rs[0] + rs[1] + rs[2] + rs[3];
        float b = rs2[0] + rs2[1] + rs2[2] + rs2[3];
        float mean = a * (1.0f / DIMC);
        float var = b * (1.0f / DIMC) - mean * mean;
        float2 o; o.x = mean; o.y = rsqrtf(var + 1e-5f);
        stats[t] = o;
    }
}

// ---------------- QKV GEMM (LN fused into A staging) ----------------
// q,k stored [B,H,dh,N] (token minor), v stored token-major [T, C]
__global__ __launch_bounds__(256) void gemm_qkv_kernel(
    const float* __restrict__ x, const float2* __restrict__ stats,
    const float* __restrict__ lng, const float* __restrict__ lnb,
    const ushort* __restrict__ wb,
    ushort* __restrict__ qb, ushort* __restrict__ kb, ushort* __restrict__ vb) {
    __shared__ __align__(16) ushort As[64][32];
    __shared__ __align__(16) ushort Bs[64][32];
    int m0 = blockIdx.x * 64, n0 = blockIdx.y * 64;
    int tid = threadIdx.x;
    int wid = tid >> 6, lane = tid & 63;
    int wr = wid >> 1, wc = wid & 1;
    int lr = tid >> 2, lc = (tid & 3) * 8;
    f32x4 acc[2][2] = {};
    float2 st = stats[m0 + lr];
    const float* xrow = x + (size_t)(m0 + lr) * DIMC;
    const ushort* wrow = wb + (size_t)(n0 + lr) * DIMC;
    for (int kk = 0; kk < DIMC; kk += 32) {
        __syncthreads();
        float xa[8], ga[8], ba[8];
        *(float4*)&xa[0] = *(const float4*)&xrow[kk + lc];
        *(float4*)&xa[4] = *(const float4*)&xrow[kk + lc + 4];
        *(float4*)&ga[0] = *(const float4*)&lng[kk + lc];
        *(float4*)&ga[4] = *(const float4*)&lng[kk + lc + 4];
        *(float4*)&ba[0] = *(const float4*)&lnb[kk + lc];
        *(float4*)&ba[4] = *(const float4*)&lnb[kk + lc + 4];
        short8 av;
#pragma unroll
        for (int u = 0; u < 8; u++)
            av[u] = (short)f2bf((xa[u] - st.x) * st.y * ga[u] + ba[u]);
        *(short8*)&As[lr][lc] = av;
        *(short8*)&Bs[lr][lc] = *(const short8*)&wrow[kk + lc];
        __syncthreads();
        short8 af[2], bfr[2];
#pragma unroll
        for (int i = 0; i < 2; i++)
            af[i] = *(const short8*)&As[wr * 32 + i * 16 + (lane & 15)][(lane >> 4) * 8];
#pragma unroll
        for (int j = 0; j < 2; j++)
            bfr[j] = *(const short8*)&Bs[wc * 32 + j * 16 + (lane & 15)][(lane >> 4) * 8];
#pragma unroll
        for (int i = 0; i < 2; i++)
#pragma unroll
            for (int j = 0; j < 2; j++)
                acc[i][j] = __builtin_amdgcn_mfma_f32_16x16x32_bf16(af[i], bfr[j], acc[i][j], 0, 0, 0);
    }
#pragma unroll
    for (int i = 0; i < 2; i++) {
#pragma unroll
        for (int j = 0; j < 2; j++) {
            int o = n0 + wc * 32 + j * 16 + (lane & 15);
#pragma unroll
            for (int qq = 0; qq < 4; qq++) {
                int r = m0 + wr * 32 + i * 16 + (lane >> 4) * 4 + qq;
                ushort val = f2bf(acc[i][j][qq]);
                if (o < DIMC) {
                    int h = o / DH, d = o - h * DH;
                    int b_ = r >> 12, n = r & (NPB - 1);
                    qb[(((size_t)b_ * HEADS + h) * DH + d) * NPB + n] = val;
                } else if (o < 2 * DIMC) {
                    int oo = o - DIMC;
                    int h = oo / DH, d = oo - h * DH;
                    int b_ = r >> 12, n = r & (NPB - 1);
                    kb[(((size_t)b_ * HEADS + h) * DH + d) * NPB + n] = val;
                } else {
                    vb[(size_t)r * DIMC + (o - 2 * DIMC)] = val;
                }
            }
        }
    }
}

// ---------------- column L2 norms over tokens for q and k ----------------
__global__ __launch_bounds__(256) void colnorm_kernel(
    const ushort* __restrict__ qb, const ushort* __restrict__ kb,
    float* __restrict__ rq, float* __restrict__ rk) {
    int row = blockIdx.x;  // 0..12287 ; 6144 rows each for q,k
    const ushort* src = (row < 6144) ? (qb + (size_t)row * NPB)
                                     : (kb + (size_t)(row - 6144) * NPB);
    int tid = threadIdx.x;
    float s = 0.f;
#pragma unroll
    for (int u = 0; u < 2; u++) {
        short8 v = *(const short8*)&src[tid * 16 + u * 8];
#pragma unroll
        for (int e = 0; e < 8; e++) { float f = bf2f((ushort)v[e]); s += f * f; }
    }
#pragma unroll
    for (int off = 32; off > 0; off >>= 1) s += __shfl_down(s, off);
    __shared__ float rs[4];
    int wid = tid >> 6, lane = tid & 63;
    if (lane == 0) rs[wid] = s;
    __syncthreads();
    if (tid == 0) {
        float tot = rs[0] + rs[1] + rs[2] + rs[3];
        float inv = 1.0f / fmaxf(sqrtf(tot), 1e-12f);
        if (row < 6144) rq[row] = inv; else rk[row - 6144] = inv;
    }
}

// ---------------- attention: attn = softmax(q^ k^T * temp) ----------------
// one block per (b,h); 9 waves, each a 32x32 tile of the 96x96 output
__global__ __launch_bounds__(576) void attn_kernel(
    const ushort* __restrict__ qb, const ushort* __restrict__ kb,
    const float* __restrict__ rq, const float* __restrict__ rk,
    const float* __restrict__ temp, ushort* __restrict__ attnb) {
    int bh = blockIdx.x;
    int tid = threadIdx.x;
    int wid = tid >> 6, lane = tid & 63;
    int wr = wid / 3, wc = wid - wr * 3;
    const ushort* qrow = qb + (size_t)bh * DH * NPB;
    const ushort* krow = kb + (size_t)bh * DH * NPB;
    f32x4 acc[2][2] = {};
    for (int n = 0; n < NPB; n += 32) {
        short8 a[2], bfr[2];
#pragma unroll
        for (int i = 0; i < 2; i++)
            a[i] = *(const short8*)&qrow[(size_t)(wr * 32 + i * 16 + (lane & 15)) * NPB + n + (lane >> 4) * 8];
#pragma unroll
        for (int j = 0; j < 2; j++)
            bfr[j] = *(const short8*)&krow[(size_t)(wc * 32 + j * 16 + (lane & 15)) * NPB + n + (lane >> 4) * 8];
#pragma unroll
        for (int i = 0; i < 2; i++)
#pragma unroll
            for (int j = 0; j < 2; j++)
                acc[i][j] = __builtin_amdgcn_mfma_f32_16x16x32_bf16(a[i], bfr[j], acc[i][j], 0, 0, 0);
    }
    __shared__ float sm[96][97];
    float tval = temp[bh & (HEADS - 1)];
#pragma unroll
    for (int i = 0; i < 2; i++)
#pragma unroll
        for (int j = 0; j < 2; j++) {
            int e = wc * 32 + j * 16 + (lane & 15);
            float rke = rk[bh * DH + e];
#pragma unroll
            for (int qq = 0; qq < 4; qq++) {
                int d = wr * 32 + i * 16 + (lane >> 4) * 4 + qq;
                sm[d][e] = acc[i][j][qq] * rq[bh * DH + d] * rke * tval;
            }
        }
    __syncthreads();
    if (tid < 96) {
        int d = tid;
        float m = -1e30f;
        for (int e = 0; e < 96; e++) m = fmaxf(m, sm[d][e]);
        float ssum = 0.f;
        for (int e = 0; e < 96; e++) { float ex = expf(sm[d][e] - m); sm[d][e] = ex; ssum += ex; }
        float inv = 1.0f / ssum;
        for (int e = 0; e < 96; e++)
            attnb[(size_t)bh * (DH * DH) + d * DH + e] = f2bf(sm[d][e] * inv);
    }
}

// ---------------- PV: out_t[t][h*96+d] = sum_e attn[d,e] * v[t][h*96+e] ----
__global__ __launch_bounds__(256) void pv_kernel(
    const ushort* __restrict__ attnb, const ushort* __restrict__ vb,
    ushort* __restrict__ outt) {
    int tt = blockIdx.x;   // 0..31 token tiles of 128 (within batch)
    int bh = blockIdx.y;   // 0..63
    int b_ = bh >> 3, h = bh & 7;
    int tid = threadIdx.x;
    int wid = tid >> 6, lane = tid & 63;
    int t0 = b_ * NPB + tt * 128;
    const ushort* A = vb + (size_t)t0 * DIMC + h * DH;
    const ushort* Bm = attnb + (size_t)bh * (DH * DH);
    f32x4 acc[2][6] = {};
#pragma unroll
    for (int kk = 0; kk < DH; kk += 32) {
        short8 a[2];
#pragma unroll
        for (int i = 0; i < 2; i++)
            a[i] = *(const short8*)&A[(size_t)(wid * 32 + i * 16 + (lane & 15)) * DIMC + kk + (lane >> 4) * 8];
#pragma unroll
        for (int j = 0; j < 6; j++) {
            short8 bfr = *(const short8*)&Bm[(j * 16 + (lane & 15)) * DH + kk + (lane >> 4) * 8];
#pragma unroll
            for (int i = 0; i < 2; i++)
                acc[i][j] = __builtin_amdgcn_mfma_f32_16x16x32_bf16(a[i], bfr, acc[i][j], 0, 0, 0);
        }
    }
#pragma unroll
    for (int i = 0; i < 2; i++)
#pragma unroll
        for (int j = 0; j < 6; j++) {
            int d = j * 16 + (lane & 15);
#pragma unroll
            for (int qq = 0; qq < 4; qq++) {
                int t = t0 + wid * 32 + i * 16 + (lane >> 4) * 4 + qq;
                outt[(size_t)t * DIMC + h * DH + d] = f2bf(acc[i][j][qq]);
            }
        }
}

// ---------------- proj GEMM + bias + gamma1 + residual ----------------
__global__ __launch_bounds__(256) void gemm_proj_kernel(
    const ushort* __restrict__ outt, const ushort* __restrict__ pwb,
    const float* __restrict__ pb, const float* __restrict__ g1,
    const float* __restrict__ x, float* __restrict__ out) {
    __shared__ __align__(16) ushort As[64][32];
    __shared__ __align__(16) ushort Bs[64][32];
    int m0 = blockIdx.x * 64, n0 = blockIdx.y * 64;
    int tid = threadIdx.x;
    int wid = tid >> 6, lane = tid & 63;
    int wr = wid >> 1, wc = wid & 1;
    int lr = tid >> 2, lc = (tid & 3) * 8;
    const ushort* arow = outt + (size_t)(m0 + lr) * DIMC;
    const ushort* brow = pwb + (size_t)(n0 + lr) * DIMC;
    f32x4 acc[2][2] = {};
    for (int kk = 0; kk < DIMC; kk += 32) {
        __syncthreads();
        *(short8*)&As[lr][lc] = *(const short8*)&arow[kk + lc];
        *(short8*)&Bs[lr][lc] = *(const short8*)&brow[kk + lc];
        __syncthreads();
        short8 af[2], bfr[2];
#pragma unroll
        for (int i = 0; i < 2; i++)
            af[i] = *(const short8*)&As[wr * 32 + i * 16 + (lane & 15)][(lane >> 4) * 8];
#pragma unroll
        for (int j = 0; j < 2; j++)
            bfr[j] = *(const short8*)&Bs[wc * 32 + j * 16 + (lane & 15)][(lane >> 4) * 8];
#pragma unroll
        for (int i = 0; i < 2; i++)
#pragma unroll
            for (int j = 0; j < 2; j++)
                acc[i][j] = __builtin_amdgcn_mfma_f32_16x16x32_bf16(af[i], bfr[j], acc[i][j], 0, 0, 0);
    }
#pragma unroll
    for (int i = 0; i < 2; i++)
#pragma unroll
        for (int j = 0; j < 2; j++) {
            int o = n0 + wc * 32 + j * 16 + (lane & 15);
            float pbo = pb[o], g1o = g1[o];
#pragma unroll
            for (int qq = 0; qq < 4; qq++) {
                int r = m0 + wr * 32 + i * 16 + (lane >> 4) * 4 + qq;
                size_t idx = (size_t)r * DIMC + o;
                out[idx] = g1o * (acc[i][j][qq] + pbo) + x[idx];
            }
        }
}

extern "C" void kernel_launch(void* const* d_in, const int* in_sizes, int n_in,
                              void* d_out, int out_size, void* d_ws, size_t ws_size,
                              hipStream_t stream) {
    const float* x     = (const float*)d_in[0];
    const float* qkvw  = (const float*)d_in[1];
    const float* projw = (const float*)d_in[2];
    const float* projb = (const float*)d_in[3];
    const float* lng   = (const float*)d_in[4];
    const float* lnb   = (const float*)d_in[5];
    const float* temp  = (const float*)d_in[6];
    const float* g1    = (const float*)d_in[7];
    float* out = (float*)d_out;

    char* w = (char*)d_ws;
    ushort* qb    = (ushort*)(w + 0);           // 50331648 B  [B,H,dh,N]
    ushort* kb    = (ushort*)(w + 50331648);    // 50331648 B
    ushort* vb    = (ushort*)(w + 100663296);   // 50331648 B  [T, C] token-major
    ushort* qwb   = (ushort*)(w + 150994944);   // 3538944 B
    ushort* pwb   = (ushort*)(w + 154533888);   // 1179648 B
    float2* stats = (float2*)(w + 155713536);   // 262144 B
    float*  rq    = (float*)(w + 155975680);    // 24576 B
    float*  rk    = (float*)(w + 156000256);    // 24576 B
    ushort* attnb = (ushort*)(w + 156024832);   // 1179648 B
    ushort* outt  = qb;                          // reuse q slot after attn

    hipLaunchKernelGGL(cvtw_kernel, dim3(6912), dim3(256), 0, stream, qkvw, projw, qwb, pwb);
    hipLaunchKernelGGL(ln_stats_kernel, dim3(32768), dim3(256), 0, stream, x, stats);
    hipLaunchKernelGGL(gemm_qkv_kernel, dim3(512, 36), dim3(256), 0, stream,
                       x, stats, lng, lnb, qwb, qb, kb, vb);
    hipLaunchKernelGGL(colnorm_kernel, dim3(12288), dim3(256), 0, stream, qb, kb, rq, rk);
    hipLaunchKernelGGL(attn_kernel, dim3(64), dim3(576), 0, stream, qb, kb, rq, rk, temp, attnb);
    hipLaunchKernelGGL(pv_kernel, dim3(32, 64), dim3(256), 0, stream, attnb, vb, outt);
    hipLaunchKernelGGL(gemm_proj_kernel, dim3(512, 12), dim3(256), 0, stream,
                       outt, pwb, projb, g1, x, out);
}

// Round 2
// 563.696 us; speedup vs baseline: 1.5337x; 1.5337x over previous
//
#include <hip/hip_runtime.h>
#include <hip/hip_bf16.h>
#include <stdint.h>

typedef __attribute__((ext_vector_type(8))) short short8;
typedef __attribute__((ext_vector_type(4))) float f32x4;

#define DIMC 768
#define NTOK 32768
#define NPB 4096
#define HEADS 8
#define DH 96

__device__ __forceinline__ ushort f2bf(float f) {
    union { float f; uint32_t u; } c; c.f = f;
    uint32_t u = c.u;
    u += 0x7fffu + ((u >> 16) & 1u);
    return (ushort)(u >> 16);
}
__device__ __forceinline__ float bf2f(ushort h) {
    union { uint32_t u; float f; } c; c.u = ((uint32_t)h) << 16;
    return c.f;
}
// pack 2 floats -> 2 bf16 (compiler emits v_cvt_pk_bf16_f32)
__device__ __forceinline__ uint pk2(float a, float b) {
    float2 t; t.x = a; t.y = b;
    __hip_bfloat162 h = __float22bfloat162_rn(t);
    union { __hip_bfloat162 h; uint u; } c; c.h = h; return c.u;
}

__device__ __forceinline__ void gload_lds16(const void* g, void* l) {
    __builtin_amdgcn_global_load_lds(
        (const __attribute__((address_space(1))) void*)g,
        (__attribute__((address_space(3))) void*)l, 16, 0, 0);
}

// ---------------- weight prep: qwb = bf16(g[k]*qw[o,k]); pwb = bf16(pw) ----
__global__ __launch_bounds__(256) void prep_w_kernel(
    const float* __restrict__ qw, const float* __restrict__ pw,
    const float* __restrict__ g,
    ushort* __restrict__ qwb, ushort* __restrict__ pwb) {
    int i = blockIdx.x * 256 + threadIdx.x;
    if (i < 3 * DIMC * DIMC) {
        int k = i % DIMC;
        qwb[i] = f2bf(qw[i] * g[k]);
    }
    if (i < DIMC * DIMC) pwb[i] = f2bf(pw[i]);
}

// ---------------- Sg[o] = sum_k g[k] W[o,k]; Sb[o] = sum_k b[k] W[o,k] -----
__global__ __launch_bounds__(256) void sgsb_kernel(
    const float* __restrict__ qw, const float* __restrict__ g,
    const float* __restrict__ b, float* __restrict__ sg, float* __restrict__ sb) {
    int o = blockIdx.x * 4 + (threadIdx.x >> 6);
    int lane = threadIdx.x & 63;
    const float* wr = qw + (size_t)o * DIMC;
    float s1 = 0.f, s2 = 0.f;
    for (int k = lane; k < DIMC; k += 64) {
        float w = wr[k];
        s1 += w * g[k];
        s2 += w * b[k];
    }
#pragma unroll
    for (int off = 32; off > 0; off >>= 1) {
        s1 += __shfl_down(s1, off);
        s2 += __shfl_down(s2, off);
    }
    if (lane == 0) { sg[o] = s1; sb[o] = s2; }
}

// ---------------- LayerNorm stats (mean, rstd) per token ----------------
__global__ __launch_bounds__(256) void ln_stats_kernel(
    const float* __restrict__ x, float2* __restrict__ stats) {
    int t = blockIdx.x;
    int tid = threadIdx.x;
    const float* xr = x + (size_t)t * DIMC;
    float v0 = xr[tid], v1 = xr[tid + 256], v2 = xr[tid + 512];
    float s = v0 + v1 + v2;
    float s2 = v0 * v0 + v1 * v1 + v2 * v2;
#pragma unroll
    for (int off = 32; off > 0; off >>= 1) {
        s  += __shfl_down(s, off);
        s2 += __shfl_down(s2, off);
    }
    __shared__ float rs[4], rs2[4];
    int wid = tid >> 6, lane = tid & 63;
    if (lane == 0) { rs[wid] = s; rs2[wid] = s2; }
    __syncthreads();
    if (tid == 0) {
        float a = rs[0] + rs[1] + rs[2] + rs[3];
        float b = rs2[0] + rs2[1] + rs2[2] + rs2[3];
        float mean = a * (1.0f / DIMC);
        float var = b * (1.0f / DIMC) - mean * mean;
        float2 o; o.x = mean; o.y = rsqrtf(var + 1e-5f);
        stats[t] = o;
    }
}

// ---------------- QKV GEMM: 128x128 tile, BK=32, LN folded into epilogue ---
// A = bf16(x) reg-staged, B = qwb via global_load_lds.
__global__ __launch_bounds__(256) void gemm_qkv_kernel(
    const float* __restrict__ x, const float2* __restrict__ stats,
    const float* __restrict__ sg, const float* __restrict__ sb,
    const ushort* __restrict__ wb,
    ushort* __restrict__ qb, ushort* __restrict__ kb, ushort* __restrict__ vb) {
    __shared__ __align__(16) ushort As[128 * 32];
    __shared__ __align__(16) ushort Bs[128 * 32];
    int m0 = blockIdx.x * 128, n0 = blockIdx.y * 128;
    int tid = threadIdx.x;
    int wid = tid >> 6, lane = tid & 63;
    int wr = wid >> 1, wc = wid & 1;
    int k8 = lane >> 4, l15 = lane & 15;
    // A staging map: chunk c8 (16B of fp32 = 4 cols), row group rg (4 rows)
    int c8 = tid & 7, rg = tid >> 3;
    const float* abase = x + (size_t)(m0 + rg * 4) * DIMC + c8 * 4;
    // B staging map
    int brow = tid >> 2, bcol = (tid & 3) * 8;
    const ushort* bbase = wb + (size_t)(n0 + brow) * DIMC + bcol;

    f32x4 acc[4][4] = {};
    float4 av[4];
    // prologue: issue A loads for kk=0
#pragma unroll
    for (int u = 0; u < 4; u++)
        av[u] = *(const float4*)(abase + (size_t)u * DIMC);

    for (int kk = 0; kk < DIMC; kk += 32) {
        __syncthreads();   // LDS free (also drains in-flight A loads)
        // cvt A -> LDS
#pragma unroll
        for (int u = 0; u < 4; u++) {
            uint2 w;
            w.x = pk2(av[u].x, av[u].y);
            w.y = pk2(av[u].z, av[u].w);
            *(uint2*)&As[(rg * 4 + u) * 32 + c8 * 4] = w;
        }
        // B -> LDS via async DMA
#pragma unroll
        for (int it = 0; it < 2; it++)
            gload_lds16(bbase + kk + (size_t)it * 64 * DIMC,
                        &Bs[it * 2048 + tid * 8]);
        __syncthreads();
        short8 af[4], bfv[4];
#pragma unroll
        for (int i = 0; i < 4; i++)
            af[i] = *(const short8*)&As[(wr * 64 + i * 16 + l15) * 32 + k8 * 8];
#pragma unroll
        for (int j = 0; j < 4; j++)
            bfv[j] = *(const short8*)&Bs[(wc * 64 + j * 16 + l15) * 32 + k8 * 8];
        // prefetch next A tile during MFMA phase
        if (kk + 32 < DIMC) {
#pragma unroll
            for (int u = 0; u < 4; u++)
                av[u] = *(const float4*)(abase + (size_t)u * DIMC + kk + 32);
        }
#pragma unroll
        for (int i = 0; i < 4; i++)
#pragma unroll
            for (int j = 0; j < 4; j++)
                acc[i][j] = __builtin_amdgcn_mfma_f32_16x16x32_bf16(af[i], bfv[j], acc[i][j], 0, 0, 0);
    }

    int seg = (n0 >= 2 * DIMC) ? 2 : ((n0 >= DIMC) ? 1 : 0);
#pragma unroll
    for (int i = 0; i < 4; i++) {
        float2 st4[4];
#pragma unroll
        for (int qq = 0; qq < 4; qq++)
            st4[qq] = stats[m0 + wr * 64 + i * 16 + k8 * 4 + qq];
#pragma unroll
        for (int j = 0; j < 4; j++) {
            int o = n0 + wc * 64 + j * 16 + l15;
            float sgo = sg[o], sbo = sb[o];
            int oL = o - seg * DIMC;
            int h = oL / DH, d = oL - h * DH;
#pragma unroll
            for (int qq = 0; qq < 4; qq++) {
                int r = m0 + wr * 64 + i * 16 + k8 * 4 + qq;
                float val = st4[qq].y * (acc[i][j][qq] - st4[qq].x * sgo) + sbo;
                ushort vb16 = f2bf(val);
                int b_ = r >> 12, n = r & (NPB - 1);
                if (seg == 0)
                    qb[(((size_t)b_ * HEADS + h) * DH + d) * NPB + n] = vb16;
                else if (seg == 1)
                    kb[(((size_t)b_ * HEADS + h) * DH + d) * NPB + n] = vb16;
                else
                    vb[(size_t)r * DIMC + oL] = vb16;
            }
        }
    }
}

// ---------------- column L2 norms over tokens for q and k ----------------
__global__ __launch_bounds__(256) void colnorm_kernel(
    const ushort* __restrict__ qb, const ushort* __restrict__ kb,
    float* __restrict__ rq, float* __restrict__ rk) {
    int row = blockIdx.x;  // 0..12287 ; 6144 rows each for q,k
    const ushort* src = (row < 6144) ? (qb + (size_t)row * NPB)
                                     : (kb + (size_t)(row - 6144) * NPB);
    int tid = threadIdx.x;
    float s = 0.f;
#pragma unroll
    for (int u = 0; u < 2; u++) {
        short8 v = *(const short8*)&src[tid * 16 + u * 8];
#pragma unroll
        for (int e = 0; e < 8; e++) { float f = bf2f((ushort)v[e]); s += f * f; }
    }
#pragma unroll
    for (int off = 32; off > 0; off >>= 1) s += __shfl_down(s, off);
    __shared__ float rs[4];
    int wid = tid >> 6, lane = tid & 63;
    if (lane == 0) rs[wid] = s;
    __syncthreads();
    if (tid == 0) {
        float tot = rs[0] + rs[1] + rs[2] + rs[3];
        float inv = 1.0f / fmaxf(sqrtf(tot), 1e-12f);
        if (row < 6144) rq[row] = inv; else rk[row - 6144] = inv;
    }
}

// ---------------- attention: softmax(q^ k^T * temp), d-split across blocks -
// grid (64, 3): block = (b*8+h, d-slice of 32 rows); 3 waves, each 32x32
__global__ __launch_bounds__(192) void attn_kernel(
    const ushort* __restrict__ qb, const ushort* __restrict__ kb,
    const float* __restrict__ rq, const float* __restrict__ rk,
    const float* __restrict__ temp, ushort* __restrict__ attnb) {
    int bh = blockIdx.x;
    int ds0 = blockIdx.y * 32;
    int tid = threadIdx.x;
    int wid = tid >> 6, lane = tid & 63;
    int k8 = lane >> 4, l15 = lane & 15;
    const ushort* qrow = qb + ((size_t)bh * DH + ds0) * NPB;
    const ushort* krow = kb + (size_t)bh * DH * NPB;
    f32x4 acc[2][2] = {};
    for (int n = 0; n < NPB; n += 32) {
        short8 a[2], b[2];
#pragma unroll
        for (int i = 0; i < 2; i++)
            a[i] = *(const short8*)&qrow[(size_t)(i * 16 + l15) * NPB + n + k8 * 8];
#pragma unroll
        for (int j = 0; j < 2; j++)
            b[j] = *(const short8*)&krow[(size_t)(wid * 32 + j * 16 + l15) * NPB + n + k8 * 8];
#pragma unroll
        for (int i = 0; i < 2; i++)
#pragma unroll
            for (int j = 0; j < 2; j++)
                acc[i][j] = __builtin_amdgcn_mfma_f32_16x16x32_bf16(a[i], b[j], acc[i][j], 0, 0, 0);
    }
    __shared__ float sm[32][97];
    __shared__ float red[32][16];
    float tval = temp[bh & (HEADS - 1)];
#pragma unroll
    for (int i = 0; i < 2; i++)
#pragma unroll
        for (int j = 0; j < 2; j++) {
            int e = wid * 32 + j * 16 + l15;
            float rke = rk[bh * DH + e] * tval;
#pragma unroll
            for (int qq = 0; qq < 4; qq++) {
                int d = i * 16 + k8 * 4 + qq;
                sm[d][e] = acc[i][j][qq] * rq[bh * DH + ds0 + d] * rke;
            }
        }
    __syncthreads();
    // parallel softmax: 192 threads = 32 rows x 6 parts of 16 cols
    int r = tid & 31, p = tid >> 5;
    float lm = -3.4e38f;
#pragma unroll
    for (int c = 0; c < 16; c++) lm = fmaxf(lm, sm[r][p * 16 + c]);
    red[r][p] = lm;
    __syncthreads();
    float m = red[r][0];
#pragma unroll
    for (int t = 1; t < 6; t++) m = fmaxf(m, red[r][t]);
    float s = 0.f;
#pragma unroll
    for (int c = 0; c < 16; c++) {
        float ex = __expf(sm[r][p * 16 + c] - m);
        sm[r][p * 16 + c] = ex;
        s += ex;
    }
    __syncthreads();
    red[r][8 + p] = s;
    __syncthreads();
    float tot = red[r][8];
#pragma unroll
    for (int t = 1; t < 6; t++) tot += red[r][8 + t];
    float inv = 1.0f / tot;
    size_t obase = (size_t)bh * (DH * DH) + (size_t)(ds0 + r) * DH + p * 16;
#pragma unroll
    for (int c = 0; c < 16; c++)
        attnb[obase + c] = f2bf(sm[r][p * 16 + c] * inv);
}

// ---------------- PV: out_t[t][h*96+d] = sum_e attn[d,e] * v[t][h*96+e] ----
__global__ __launch_bounds__(256) void pv_kernel(
    const ushort* __restrict__ attnb, const ushort* __restrict__ vb,
    ushort* __restrict__ outt) {
    int tt = blockIdx.x;   // 0..31 token tiles of 128 (within batch)
    int bh = blockIdx.y;   // 0..63
    int b_ = bh >> 3, h = bh & 7;
    int tid = threadIdx.x;
    int wid = tid >> 6, lane = tid & 63;
    int k8 = lane >> 4, l15 = lane & 15;
    int t0 = b_ * NPB + tt * 128;
    const ushort* A = vb + (size_t)t0 * DIMC + h * DH;
    const ushort* Bm = attnb + (size_t)bh * (DH * DH);
    f32x4 acc[2][6] = {};
#pragma unroll
    for (int kk = 0; kk < DH; kk += 32) {
        short8 a[2];
#pragma unroll
        for (int i = 0; i < 2; i++)
            a[i] = *(const short8*)&A[(size_t)(wid * 32 + i * 16 + l15) * DIMC + kk + k8 * 8];
#pragma unroll
        for (int j = 0; j < 6; j++) {
            short8 bfr = *(const short8*)&Bm[(j * 16 + l15) * DH + kk + k8 * 8];
#pragma unroll
            for (int i = 0; i < 2; i++)
                acc[i][j] = __builtin_amdgcn_mfma_f32_16x16x32_bf16(a[i], bfr, acc[i][j], 0, 0, 0);
        }
    }
#pragma unroll
    for (int i = 0; i < 2; i++)
#pragma unroll
        for (int j = 0; j < 6; j++) {
            int d = j * 16 + l15;
#pragma unroll
            for (int qq = 0; qq < 4; qq++) {
                int t = t0 + wid * 32 + i * 16 + k8 * 4 + qq;
                outt[(size_t)t * DIMC + h * DH + d] = f2bf(acc[i][j][qq]);
            }
        }
}

// ---------------- proj GEMM 128x128 + bias + gamma1 + residual -------------
__global__ __launch_bounds__(256) void gemm_proj_kernel(
    const ushort* __restrict__ outt, const ushort* __restrict__ pwb,
    const float* __restrict__ pb, const float* __restrict__ g1,
    const float* __restrict__ x, float* __restrict__ out) {
    __shared__ __align__(16) ushort As[128 * 32];
    __shared__ __align__(16) ushort Bs[128 * 32];
    int m0 = blockIdx.x * 128, n0 = blockIdx.y * 128;
    int tid = threadIdx.x;
    int wid = tid >> 6, lane = tid & 63;
    int wr = wid >> 1, wc = wid & 1;
    int k8 = lane >> 4, l15 = lane & 15;
    int srow = tid >> 2, scol = (tid & 3) * 8;
    const ushort* abase = outt + (size_t)(m0 + srow) * DIMC + scol;
    const ushort* bbase = pwb + (size_t)(n0 + srow) * DIMC + scol;
    f32x4 acc[4][4] = {};
    for (int kk = 0; kk < DIMC; kk += 32) {
        __syncthreads();
#pragma unroll
        for (int it = 0; it < 2; it++) {
            gload_lds16(abase + kk + (size_t)it * 64 * DIMC, &As[it * 2048 + tid * 8]);
            gload_lds16(bbase + kk + (size_t)it * 64 * DIMC, &Bs[it * 2048 + tid * 8]);
        }
        __syncthreads();
        short8 af[4], bfv[4];
#pragma unroll
        for (int i = 0; i < 4; i++)
            af[i] = *(const short8*)&As[(wr * 64 + i * 16 + l15) * 32 + k8 * 8];
#pragma unroll
        for (int j = 0; j < 4; j++)
            bfv[j] = *(const short8*)&Bs[(wc * 64 + j * 16 + l15) * 32 + k8 * 8];
#pragma unroll
        for (int i = 0; i < 4; i++)
#pragma unroll
            for (int j = 0; j < 4; j++)
                acc[i][j] = __builtin_amdgcn_mfma_f32_16x16x32_bf16(af[i], bfv[j], acc[i][j], 0, 0, 0);
    }
#pragma unroll
    for (int i = 0; i < 4; i++)
#pragma unroll
        for (int j = 0; j < 4; j++) {
            int o = n0 + wc * 64 + j * 16 + l15;
            float pbo = pb[o], g1o = g1[o];
#pragma unroll
            for (int qq = 0; qq < 4; qq++) {
                int r = m0 + wr * 64 + i * 16 + k8 * 4 + qq;
                size_t idx = (size_t)r * DIMC + o;
                out[idx] = g1o * (acc[i][j][qq] + pbo) + x[idx];
            }
        }
}

extern "C" void kernel_launch(void* const* d_in, const int* in_sizes, int n_in,
                              void* d_out, int out_size, void* d_ws, size_t ws_size,
                              hipStream_t stream) {
    const float* x     = (const float*)d_in[0];
    const float* qkvw  = (const float*)d_in[1];
    const float* projw = (const float*)d_in[2];
    const float* projb = (const float*)d_in[3];
    const float* lng   = (const float*)d_in[4];
    const float* lnb   = (const float*)d_in[5];
    const float* temp  = (const float*)d_in[6];
    const float* g1    = (const float*)d_in[7];
    float* out = (float*)d_out;

    char* w = (char*)d_ws;
    ushort* qb    = (ushort*)(w + 0);            // 50,331,648  [B,H,dh,N]
    ushort* kb    = (ushort*)(w + 50331648);     // 50,331,648
    ushort* vb    = (ushort*)(w + 100663296);    // 50,331,648  [T, C] token-major
    ushort* qwb   = (ushort*)(w + 150994944);    // 3,538,944
    ushort* pwb   = (ushort*)(w + 154533888);    // 1,179,648
    float*  rq    = (float*)(w + 155713536);     // 24,576
    float*  rk    = (float*)(w + 155738112);     // 24,576
    float*  sg    = (float*)(w + 155762688);     // 9,216   (dead after qkv GEMM)
    float*  sb    = (float*)(w + 155771904);     // 9,216   (dead after qkv GEMM)
    ushort* attnb = (ushort*)(w + 155762688);    // 1,179,648 (aliases sg/sb)
    float2* stats = (float2*)(w + 156942336);    // 262,144  -> total 157,204,480
    ushort* outt  = qb;                          // reuse q slot after attn

    hipLaunchKernelGGL(prep_w_kernel, dim3(6912), dim3(256), 0, stream,
                       qkvw, projw, lng, qwb, pwb);
    hipLaunchKernelGGL(sgsb_kernel, dim3(576), dim3(256), 0, stream,
                       qkvw, lng, lnb, sg, sb);
    hipLaunchKernelGGL(ln_stats_kernel, dim3(32768), dim3(256), 0, stream, x, stats);
    hipLaunchKernelGGL(gemm_qkv_kernel, dim3(256, 18), dim3(256), 0, stream,
                       x, stats, sg, sb, qwb, qb, kb, vb);
    hipLaunchKernelGGL(colnorm_kernel, dim3(12288), dim3(256), 0, stream, qb, kb, rq, rk);
    hipLaunchKernelGGL(attn_kernel, dim3(64, 3), dim3(192), 0, stream,
                       qb, kb, rq, rk, temp, attnb);
    hipLaunchKernelGGL(pv_kernel, dim3(32, 64), dim3(256), 0, stream, attnb, vb, outt);
    hipLaunchKernelGGL(gemm_proj_kernel, dim3(256, 6), dim3(256), 0, stream,
                       outt, pwb, projb, g1, x, out);
}

// Round 3
// 415.534 us; speedup vs baseline: 2.0805x; 1.3566x over previous
//
#include <hip/hip_runtime.h>
#include <hip/hip_bf16.h>
#include <stdint.h>

typedef __attribute__((ext_vector_type(8))) short short8;
typedef __attribute__((ext_vector_type(4))) float f32x4;
typedef __attribute__((ext_vector_type(4))) unsigned short us4;

#define DIMC 768
#define NTOK 32768
#define NPB 4096
#define HEADS 8
#define DH 96

__device__ __forceinline__ ushort f2bf(float f) {
    union { float f; uint32_t u; } c; c.f = f;
    uint32_t u = c.u;
    u += 0x7fffu + ((u >> 16) & 1u);
    return (ushort)(u >> 16);
}
__device__ __forceinline__ float bf2f(ushort h) {
    union { uint32_t u; float f; } c; c.u = ((uint32_t)h) << 16;
    return c.f;
}
// pack 2 floats -> 2 bf16 (compiler emits v_cvt_pk_bf16_f32)
__device__ __forceinline__ uint pk2(float a, float b) {
    float2 t; t.x = a; t.y = b;
    __hip_bfloat162 h = __float22bfloat162_rn(t);
    union { __hip_bfloat162 h; uint u; } c; c.h = h; return c.u;
}

__device__ __forceinline__ void gload_lds16(const void* g, void* l) {
    __builtin_amdgcn_global_load_lds(
        (const __attribute__((address_space(1))) void*)g,
        (__attribute__((address_space(3))) void*)l, 16, 0, 0);
}

// ---------------- weight prep: qwb = bf16(g[k]*qw[o,k]); pwb = bf16(pw) ----
__global__ __launch_bounds__(256) void prep_w_kernel(
    const float* __restrict__ qw, const float* __restrict__ pw,
    const float* __restrict__ g,
    ushort* __restrict__ qwb, ushort* __restrict__ pwb) {
    int i = blockIdx.x * 256 + threadIdx.x;
    if (i < 3 * DIMC * DIMC) {
        int k = i % DIMC;
        qwb[i] = f2bf(qw[i] * g[k]);
    }
    if (i < DIMC * DIMC) pwb[i] = f2bf(pw[i]);
}

// ---------------- Sg[o] = sum_k g[k] W[o,k]; Sb[o] = sum_k b[k] W[o,k] -----
__global__ __launch_bounds__(256) void sgsb_kernel(
    const float* __restrict__ qw, const float* __restrict__ g,
    const float* __restrict__ b, float* __restrict__ sg, float* __restrict__ sb) {
    int o = blockIdx.x * 4 + (threadIdx.x >> 6);
    int lane = threadIdx.x & 63;
    const float* wr = qw + (size_t)o * DIMC;
    float s1 = 0.f, s2 = 0.f;
    for (int k = lane; k < DIMC; k += 64) {
        float w = wr[k];
        s1 += w * g[k];
        s2 += w * b[k];
    }
#pragma unroll
    for (int off = 32; off > 0; off >>= 1) {
        s1 += __shfl_down(s1, off);
        s2 += __shfl_down(s2, off);
    }
    if (lane == 0) { sg[o] = s1; sb[o] = s2; }
}

// ---------------- LayerNorm stats (mean, rstd) per token ----------------
__global__ __launch_bounds__(256) void ln_stats_kernel(
    const float* __restrict__ x, float2* __restrict__ stats) {
    int t = blockIdx.x;
    int tid = threadIdx.x;
    const float* xr = x + (size_t)t * DIMC;
    float v0 = xr[tid], v1 = xr[tid + 256], v2 = xr[tid + 512];
    float s = v0 + v1 + v2;
    float s2 = v0 * v0 + v1 * v1 + v2 * v2;
#pragma unroll
    for (int off = 32; off > 0; off >>= 1) {
        s  += __shfl_down(s, off);
        s2 += __shfl_down(s2, off);
    }
    __shared__ float rs[4], rs2[4];
    int wid = tid >> 6, lane = tid & 63;
    if (lane == 0) { rs[wid] = s; rs2[wid] = s2; }
    __syncthreads();
    if (tid == 0) {
        float a = rs[0] + rs[1] + rs[2] + rs[3];
        float b = rs2[0] + rs2[1] + rs2[2] + rs2[3];
        float mean = a * (1.0f / DIMC);
        float var = b * (1.0f / DIMC) - mean * mean;
        float2 o; o.x = mean; o.y = rsqrtf(var + 1e-5f);
        stats[t] = o;
    }
}

// ---------------- QKV GEMM: 128x128 tile, BK=32, LN folded into epilogue ---
// grid: 4608 blocks 1D, XCD-chunk swizzled, n-tile fastest (x-slab L2 reuse)
__global__ __launch_bounds__(256) void gemm_qkv_kernel(
    const float* __restrict__ x, const float2* __restrict__ stats,
    const float* __restrict__ sg, const float* __restrict__ sb,
    const ushort* __restrict__ wb,
    ushort* __restrict__ qb, ushort* __restrict__ kb, ushort* __restrict__ vb) {
    __shared__ __align__(16) ushort As[128 * 32];
    __shared__ __align__(16) ushort Bs[128 * 32];
    int orig = blockIdx.x;                  // 0..4607
    int wg = (orig & 7) * 576 + (orig >> 3);
    int nt = wg % 18, mt = wg / 18;
    int m0 = mt * 128, n0 = nt * 128;
    int tid = threadIdx.x;
    int wid = tid >> 6, lane = tid & 63;
    int wr = wid >> 1, wc = wid & 1;
    int k8 = lane >> 4, l15 = lane & 15;
    // A staging map: chunk c8 (16B of fp32 = 4 cols), row group rg (4 rows)
    int c8 = tid & 7, rg = tid >> 3;
    const float* abase = x + (size_t)(m0 + rg * 4) * DIMC + c8 * 4;
    // B staging map
    int brow = tid >> 2, bcol = (tid & 3) * 8;
    const ushort* bbase = wb + (size_t)(n0 + brow) * DIMC + bcol;

    f32x4 acc[4][4] = {};
    float4 av[4];
#pragma unroll
    for (int u = 0; u < 4; u++)
        av[u] = *(const float4*)(abase + (size_t)u * DIMC);

    for (int kk = 0; kk < DIMC; kk += 32) {
        __syncthreads();
#pragma unroll
        for (int u = 0; u < 4; u++) {
            uint2 w;
            w.x = pk2(av[u].x, av[u].y);
            w.y = pk2(av[u].z, av[u].w);
            *(uint2*)&As[(rg * 4 + u) * 32 + c8 * 4] = w;
        }
#pragma unroll
        for (int it = 0; it < 2; it++)
            gload_lds16(bbase + kk + (size_t)it * 64 * DIMC,
                        &Bs[it * 2048 + tid * 8]);
        __syncthreads();
        short8 af[4], bfv[4];
#pragma unroll
        for (int i = 0; i < 4; i++)
            af[i] = *(const short8*)&As[(wr * 64 + i * 16 + l15) * 32 + k8 * 8];
#pragma unroll
        for (int j = 0; j < 4; j++)
            bfv[j] = *(const short8*)&Bs[(wc * 64 + j * 16 + l15) * 32 + k8 * 8];
        if (kk + 32 < DIMC) {
#pragma unroll
            for (int u = 0; u < 4; u++)
                av[u] = *(const float4*)(abase + (size_t)u * DIMC + kk + 32);
        }
#pragma unroll
        for (int i = 0; i < 4; i++)
#pragma unroll
            for (int j = 0; j < 4; j++)
                acc[i][j] = __builtin_amdgcn_mfma_f32_16x16x32_bf16(af[i], bfv[j], acc[i][j], 0, 0, 0);
    }

    int seg = (n0 >= 2 * DIMC) ? 2 : ((n0 >= DIMC) ? 1 : 0);
#pragma unroll
    for (int i = 0; i < 4; i++) {
        int r0 = m0 + wr * 64 + i * 16 + k8 * 4;
        float2 st4[4];
#pragma unroll
        for (int qq = 0; qq < 4; qq++) st4[qq] = stats[r0 + qq];
        int b_ = r0 >> 12, nn = r0 & (NPB - 1);
#pragma unroll
        for (int j = 0; j < 4; j++) {
            int o = n0 + wc * 64 + j * 16 + l15;
            float sgo = sg[o], sbo = sb[o];
            int oL = o - seg * DIMC;
            if (seg == 2) {
#pragma unroll
                for (int qq = 0; qq < 4; qq++)
                    vb[(size_t)(r0 + qq) * DIMC + oL] =
                        f2bf(st4[qq].y * (acc[i][j][qq] - st4[qq].x * sgo) + sbo);
            } else {
                int h = oL / DH, d = oL - h * DH;
                us4 pk;
#pragma unroll
                for (int qq = 0; qq < 4; qq++)
                    pk[qq] = f2bf(st4[qq].y * (acc[i][j][qq] - st4[qq].x * sgo) + sbo);
                *(us4*)((seg ? kb : qb) + (((size_t)b_ * HEADS + h) * DH + d) * NPB + nn) = pk;
            }
        }
    }
}

// ---------------- column L2 norms over tokens for q and k ----------------
__global__ __launch_bounds__(256) void colnorm_kernel(
    const ushort* __restrict__ qb, const ushort* __restrict__ kb,
    float* __restrict__ rq, float* __restrict__ rk) {
    int row = blockIdx.x;  // 0..12287 ; 6144 rows each for q,k
    const ushort* src = (row < 6144) ? (qb + (size_t)row * NPB)
                                     : (kb + (size_t)(row - 6144) * NPB);
    int tid = threadIdx.x;
    float s = 0.f;
#pragma unroll
    for (int u = 0; u < 2; u++) {
        short8 v = *(const short8*)&src[tid * 16 + u * 8];
#pragma unroll
        for (int e = 0; e < 8; e++) { float f = bf2f((ushort)v[e]); s += f * f; }
    }
#pragma unroll
    for (int off = 32; off > 0; off >>= 1) s += __shfl_down(s, off);
    __shared__ float rs[4];
    int wid = tid >> 6, lane = tid & 63;
    if (lane == 0) rs[wid] = s;
    __syncthreads();
    if (tid == 0) {
        float tot = rs[0] + rs[1] + rs[2] + rs[3];
        float inv = 1.0f / fmaxf(sqrtf(tot), 1e-12f);
        if (row < 6144) rq[row] = inv; else rk[row - 6144] = inv;
    }
}

// ---------------- attention: softmax(q^ k^T * temp), d-split across blocks -
__global__ __launch_bounds__(192) void attn_kernel(
    const ushort* __restrict__ qb, const ushort* __restrict__ kb,
    const float* __restrict__ rq, const float* __restrict__ rk,
    const float* __restrict__ temp, ushort* __restrict__ attnb) {
    int bh = blockIdx.x;
    int ds0 = blockIdx.y * 32;
    int tid = threadIdx.x;
    int wid = tid >> 6, lane = tid & 63;
    int k8 = lane >> 4, l15 = lane & 15;
    const ushort* qrow = qb + ((size_t)bh * DH + ds0) * NPB;
    const ushort* krow = kb + (size_t)bh * DH * NPB;
    f32x4 acc[2][2] = {};
    for (int n = 0; n < NPB; n += 32) {
        short8 a[2], b[2];
#pragma unroll
        for (int i = 0; i < 2; i++)
            a[i] = *(const short8*)&qrow[(size_t)(i * 16 + l15) * NPB + n + k8 * 8];
#pragma unroll
        for (int j = 0; j < 2; j++)
            b[j] = *(const short8*)&krow[(size_t)(wid * 32 + j * 16 + l15) * NPB + n + k8 * 8];
#pragma unroll
        for (int i = 0; i < 2; i++)
#pragma unroll
            for (int j = 0; j < 2; j++)
                acc[i][j] = __builtin_amdgcn_mfma_f32_16x16x32_bf16(a[i], b[j], acc[i][j], 0, 0, 0);
    }
    __shared__ float sm[32][97];
    __shared__ float red[32][16];
    float tval = temp[bh & (HEADS - 1)];
#pragma unroll
    for (int i = 0; i < 2; i++)
#pragma unroll
        for (int j = 0; j < 2; j++) {
            int e = wid * 32 + j * 16 + l15;
            float rke = rk[bh * DH + e] * tval;
#pragma unroll
            for (int qq = 0; qq < 4; qq++) {
                int d = i * 16 + k8 * 4 + qq;
                sm[d][e] = acc[i][j][qq] * rq[bh * DH + ds0 + d] * rke;
            }
        }
    __syncthreads();
    int r = tid & 31, p = tid >> 5;
    float lm = -3.4e38f;
#pragma unroll
    for (int c = 0; c < 16; c++) lm = fmaxf(lm, sm[r][p * 16 + c]);
    red[r][p] = lm;
    __syncthreads();
    float m = red[r][0];
#pragma unroll
    for (int t = 1; t < 6; t++) m = fmaxf(m, red[r][t]);
    float s = 0.f;
#pragma unroll
    for (int c = 0; c < 16; c++) {
        float ex = __expf(sm[r][p * 16 + c] - m);
        sm[r][p * 16 + c] = ex;
        s += ex;
    }
    __syncthreads();
    red[r][8 + p] = s;
    __syncthreads();
    float tot = red[r][8];
#pragma unroll
    for (int t = 1; t < 6; t++) tot += red[r][8 + t];
    float inv = 1.0f / tot;
    size_t obase = (size_t)bh * (DH * DH) + (size_t)(ds0 + r) * DH + p * 16;
#pragma unroll
    for (int c = 0; c < 16; c++)
        attnb[obase + c] = f2bf(sm[r][p * 16 + c] * inv);
}

// ---------------- PV: out_t[t][h*96+d] = sum_e attn[d,e] * v[t][h*96+e] ----
__global__ __launch_bounds__(256) void pv_kernel(
    const ushort* __restrict__ attnb, const ushort* __restrict__ vb,
    ushort* __restrict__ outt) {
    int tt = blockIdx.x;   // 0..31 token tiles of 128 (within batch)
    int bh = blockIdx.y;   // 0..63
    int b_ = bh >> 3, h = bh & 7;
    int tid = threadIdx.x;
    int wid = tid >> 6, lane = tid & 63;
    int k8 = lane >> 4, l15 = lane & 15;
    int t0 = b_ * NPB + tt * 128;
    const ushort* A = vb + (size_t)t0 * DIMC + h * DH;
    const ushort* Bm = attnb + (size_t)bh * (DH * DH);
    f32x4 acc[2][6] = {};
#pragma unroll
    for (int kk = 0; kk < DH; kk += 32) {
        short8 a[2];
#pragma unroll
        for (int i = 0; i < 2; i++)
            a[i] = *(const short8*)&A[(size_t)(wid * 32 + i * 16 + l15) * DIMC + kk + k8 * 8];
#pragma unroll
        for (int j = 0; j < 6; j++) {
            short8 bfr = *(const short8*)&Bm[(j * 16 + l15) * DH + kk + k8 * 8];
#pragma unroll
            for (int i = 0; i < 2; i++)
                acc[i][j] = __builtin_amdgcn_mfma_f32_16x16x32_bf16(a[i], bfr, acc[i][j], 0, 0, 0);
        }
    }
#pragma unroll
    for (int i = 0; i < 2; i++)
#pragma unroll
        for (int j = 0; j < 6; j++) {
            int d = j * 16 + l15;
#pragma unroll
            for (int qq = 0; qq < 4; qq++) {
                int t = t0 + wid * 32 + i * 16 + k8 * 4 + qq;
                outt[(size_t)t * DIMC + h * DH + d] = f2bf(acc[i][j][qq]);
            }
        }
}

// ---------------- proj GEMM 128x128 + bias + gamma1 + residual -------------
// grid: 1536 blocks 1D, XCD-chunk swizzled, n-tile fastest (A-slab L2 reuse)
__global__ __launch_bounds__(256) void gemm_proj_kernel(
    const ushort* __restrict__ outt, const ushort* __restrict__ pwb,
    const float* __restrict__ pb, const float* __restrict__ g1,
    const float* __restrict__ x, float* __restrict__ out) {
    __shared__ __align__(16) ushort As[128 * 32];
    __shared__ __align__(16) ushort Bs[128 * 32];
    int orig = blockIdx.x;                  // 0..1535
    int wg = (orig & 7) * 192 + (orig >> 3);
    int nt = wg % 6, mt = wg / 6;
    int m0 = mt * 128, n0 = nt * 128;
    int tid = threadIdx.x;
    int wid = tid >> 6, lane = tid & 63;
    int wr = wid >> 1, wc = wid & 1;
    int k8 = lane >> 4, l15 = lane & 15;
    int srow = tid >> 2, scol = (tid & 3) * 8;
    const ushort* abase = outt + (size_t)(m0 + srow) * DIMC + scol;
    const ushort* bbase = pwb + (size_t)(n0 + srow) * DIMC + scol;
    f32x4 acc[4][4] = {};
    for (int kk = 0; kk < DIMC; kk += 32) {
        __syncthreads();
#pragma unroll
        for (int it = 0; it < 2; it++) {
            gload_lds16(abase + kk + (size_t)it * 64 * DIMC, &As[it * 2048 + tid * 8]);
            gload_lds16(bbase + kk + (size_t)it * 64 * DIMC, &Bs[it * 2048 + tid * 8]);
        }
        __syncthreads();
        short8 af[4], bfv[4];
#pragma unroll
        for (int i = 0; i < 4; i++)
            af[i] = *(const short8*)&As[(wr * 64 + i * 16 + l15) * 32 + k8 * 8];
#pragma unroll
        for (int j = 0; j < 4; j++)
            bfv[j] = *(const short8*)&Bs[(wc * 64 + j * 16 + l15) * 32 + k8 * 8];
#pragma unroll
        for (int i = 0; i < 4; i++)
#pragma unroll
            for (int j = 0; j < 4; j++)
                acc[i][j] = __builtin_amdgcn_mfma_f32_16x16x32_bf16(af[i], bfv[j], acc[i][j], 0, 0, 0);
    }
#pragma unroll
    for (int i = 0; i < 4; i++)
#pragma unroll
        for (int j = 0; j < 4; j++) {
            int o = n0 + wc * 64 + j * 16 + l15;
            float pbo = pb[o], g1o = g1[o];
#pragma unroll
            for (int qq = 0; qq < 4; qq++) {
                int r = m0 + wr * 64 + i * 16 + k8 * 4 + qq;
                size_t idx = (size_t)r * DIMC + o;
                out[idx] = g1o * (acc[i][j][qq] + pbo) + x[idx];
            }
        }
}

extern "C" void kernel_launch(void* const* d_in, const int* in_sizes, int n_in,
                              void* d_out, int out_size, void* d_ws, size_t ws_size,
                              hipStream_t stream) {
    const float* x     = (const float*)d_in[0];
    const float* qkvw  = (const float*)d_in[1];
    const float* projw = (const float*)d_in[2];
    const float* projb = (const float*)d_in[3];
    const float* lng   = (const float*)d_in[4];
    const float* lnb   = (const float*)d_in[5];
    const float* temp  = (const float*)d_in[6];
    const float* g1    = (const float*)d_in[7];
    float* out = (float*)d_out;

    char* w = (char*)d_ws;
    ushort* qb    = (ushort*)(w + 0);            // 50,331,648  [B,H,dh,N]
    ushort* kb    = (ushort*)(w + 50331648);     // 50,331,648
    ushort* vb    = (ushort*)(w + 100663296);    // 50,331,648  [T, C] token-major
    ushort* qwb   = (ushort*)(w + 150994944);    // 3,538,944
    ushort* pwb   = (ushort*)(w + 154533888);    // 1,179,648
    float*  rq    = (float*)(w + 155713536);     // 24,576
    float*  rk    = (float*)(w + 155738112);     // 24,576
    float*  sg    = (float*)(w + 155762688);     // 9,216   (dead after qkv GEMM)
    float*  sb    = (float*)(w + 155771904);     // 9,216   (dead after qkv GEMM)
    ushort* attnb = (ushort*)(w + 155762688);    // 1,179,648 (aliases sg/sb)
    float2* stats = (float2*)(w + 156942336);    // 262,144  -> total 157,204,480
    ushort* outt  = qb;                          // reuse q slot after attn

    hipLaunchKernelGGL(prep_w_kernel, dim3(6912), dim3(256), 0, stream,
                       qkvw, projw, lng, qwb, pwb);
    hipLaunchKernelGGL(sgsb_kernel, dim3(576), dim3(256), 0, stream,
                       qkvw, lng, lnb, sg, sb);
    hipLaunchKernelGGL(ln_stats_kernel, dim3(32768), dim3(256), 0, stream, x, stats);
    hipLaunchKernelGGL(gemm_qkv_kernel, dim3(4608), dim3(256), 0, stream,
                       x, stats, sg, sb, qwb, qb, kb, vb);
    hipLaunchKernelGGL(colnorm_kernel, dim3(12288), dim3(256), 0, stream, qb, kb, rq, rk);
    hipLaunchKernelGGL(attn_kernel, dim3(64, 3), dim3(192), 0, stream,
                       qb, kb, rq, rk, temp, attnb);
    hipLaunchKernelGGL(pv_kernel, dim3(32, 64), dim3(256), 0, stream, attnb, vb, outt);
    hipLaunchKernelGGL(gemm_proj_kernel, dim3(1536), dim3(256), 0, stream,
                       outt, pwb, projb, g1, x, out);
}

// Round 4
// 403.832 us; speedup vs baseline: 2.1408x; 1.0290x over previous
//
#include <hip/hip_runtime.h>
#include <hip/hip_bf16.h>
#include <stdint.h>

typedef __attribute__((ext_vector_type(8))) short short8;
typedef __attribute__((ext_vector_type(4))) float f32x4;
typedef __attribute__((ext_vector_type(4))) unsigned short us4;

#define DIMC 768
#define NTOK 32768
#define NPB 4096
#define HEADS 8
#define DH 96

__device__ __forceinline__ ushort f2bf(float f) {
    union { float f; uint32_t u; } c; c.f = f;
    uint32_t u = c.u;
    u += 0x7fffu + ((u >> 16) & 1u);
    return (ushort)(u >> 16);
}
__device__ __forceinline__ float bf2f(ushort h) {
    union { uint32_t u; float f; } c; c.u = ((uint32_t)h) << 16;
    return c.f;
}

__device__ __forceinline__ void gload_lds16(const void* g, void* l) {
    __builtin_amdgcn_global_load_lds(
        (const __attribute__((address_space(1))) void*)g,
        (__attribute__((address_space(3))) void*)l, 16, 0, 0);
}

// ---------------- weight prep: bf16 casts, vectorized ----------------
__global__ __launch_bounds__(256) void prep_w_kernel(
    const float* __restrict__ qw, const float* __restrict__ pw,
    ushort* __restrict__ qwb, ushort* __restrict__ pwb) {
    int i4 = (blockIdx.x * 256 + threadIdx.x) * 4;
    if (i4 < 3 * DIMC * DIMC) {
        float4 w = *(const float4*)&qw[i4];
        us4 o;
        o[0] = f2bf(w.x); o[1] = f2bf(w.y); o[2] = f2bf(w.z); o[3] = f2bf(w.w);
        *(us4*)&qwb[i4] = o;
    }
    if (i4 < DIMC * DIMC) {
        float4 w = *(const float4*)&pw[i4];
        us4 o;
        o[0] = f2bf(w.x); o[1] = f2bf(w.y); o[2] = f2bf(w.z); o[3] = f2bf(w.w);
        *(us4*)&pwb[i4] = o;
    }
}

// ---------------- LayerNorm + cast: xb = bf16(ln(x)*g + b) ----------------
// one wave per token, 4 tokens per block
__global__ __launch_bounds__(256) void ln_cvt_kernel(
    const float* __restrict__ x, const float* __restrict__ g,
    const float* __restrict__ b, ushort* __restrict__ xb) {
    int t = blockIdx.x * 4 + (threadIdx.x >> 6);
    int lane = threadIdx.x & 63;
    const float* xr = x + (size_t)t * DIMC;
    float4 v[3];
    float s = 0.f, s2 = 0.f;
#pragma unroll
    for (int u = 0; u < 3; u++) {
        v[u] = *(const float4*)&xr[u * 256 + lane * 4];
        s  += v[u].x + v[u].y + v[u].z + v[u].w;
        s2 += v[u].x * v[u].x + v[u].y * v[u].y + v[u].z * v[u].z + v[u].w * v[u].w;
    }
#pragma unroll
    for (int off = 32; off > 0; off >>= 1) {
        s  += __shfl_down(s, off);
        s2 += __shfl_down(s2, off);
    }
    s = __shfl(s, 0);
    s2 = __shfl(s2, 0);
    float mean = s * (1.0f / DIMC);
    float rstd = rsqrtf(s2 * (1.0f / DIMC) - mean * mean + 1e-5f);
    ushort* xo = xb + (size_t)t * DIMC;
#pragma unroll
    for (int u = 0; u < 3; u++) {
        float4 gv = *(const float4*)&g[u * 256 + lane * 4];
        float4 bv = *(const float4*)&b[u * 256 + lane * 4];
        us4 o;
        o[0] = f2bf((v[u].x - mean) * rstd * gv.x + bv.x);
        o[1] = f2bf((v[u].y - mean) * rstd * gv.y + bv.y);
        o[2] = f2bf((v[u].z - mean) * rstd * gv.z + bv.z);
        o[3] = f2bf((v[u].w - mean) * rstd * gv.w + bv.w);
        *(us4*)&xo[u * 256 + lane * 4] = o;
    }
}

// ---------------- QKV GEMM: pure bf16, m97 structure, both ops gload_lds ---
// grid: 4608 blocks 1D, XCD-chunk swizzled, n-tile fastest (x-slab L2 reuse)
__global__ __launch_bounds__(256) void gemm_qkv_kernel(
    const ushort* __restrict__ xb, const ushort* __restrict__ wb,
    ushort* __restrict__ qb, ushort* __restrict__ kb, ushort* __restrict__ vb) {
    __shared__ __align__(16) ushort As[128 * 32];
    __shared__ __align__(16) ushort Bs[128 * 32];
    int orig = blockIdx.x;                  // 0..4607
    int wg = (orig & 7) * 576 + (orig >> 3);
    int nt = wg % 18, mt = wg / 18;
    int m0 = mt * 128, n0 = nt * 128;
    int tid = threadIdx.x;
    int wid = tid >> 6, lane = tid & 63;
    int wr = wid >> 1, wc = wid & 1;
    int k8 = lane >> 4, l15 = lane & 15;
    int srow = tid >> 2, scol = (tid & 3) * 8;
    const ushort* abase = xb + (size_t)(m0 + srow) * DIMC + scol;
    const ushort* bbase = wb + (size_t)(n0 + srow) * DIMC + scol;

    f32x4 acc[4][4] = {};
    for (int kk = 0; kk < DIMC; kk += 32) {
        __syncthreads();
#pragma unroll
        for (int it = 0; it < 2; it++) {
            gload_lds16(abase + kk + (size_t)it * 64 * DIMC, &As[it * 2048 + tid * 8]);
            gload_lds16(bbase + kk + (size_t)it * 64 * DIMC, &Bs[it * 2048 + tid * 8]);
        }
        __syncthreads();
        short8 af[4], bfv[4];
#pragma unroll
        for (int i = 0; i < 4; i++)
            af[i] = *(const short8*)&As[(wr * 64 + i * 16 + l15) * 32 + k8 * 8];
#pragma unroll
        for (int j = 0; j < 4; j++)
            bfv[j] = *(const short8*)&Bs[(wc * 64 + j * 16 + l15) * 32 + k8 * 8];
#pragma unroll
        for (int i = 0; i < 4; i++)
#pragma unroll
            for (int j = 0; j < 4; j++)
                acc[i][j] = __builtin_amdgcn_mfma_f32_16x16x32_bf16(af[i], bfv[j], acc[i][j], 0, 0, 0);
    }

    int seg = (n0 >= 2 * DIMC) ? 2 : ((n0 >= DIMC) ? 1 : 0);
#pragma unroll
    for (int i = 0; i < 4; i++) {
        int r0 = m0 + wr * 64 + i * 16 + k8 * 4;
        int b_ = r0 >> 12, nn = r0 & (NPB - 1);
#pragma unroll
        for (int j = 0; j < 4; j++) {
            int o = n0 + wc * 64 + j * 16 + l15;
            int oL = o - seg * DIMC;
            if (seg == 2) {
#pragma unroll
                for (int qq = 0; qq < 4; qq++)
                    vb[(size_t)(r0 + qq) * DIMC + oL] = f2bf(acc[i][j][qq]);
            } else {
                int h = oL / DH, d = oL - h * DH;
                us4 pk;
#pragma unroll
                for (int qq = 0; qq < 4; qq++) pk[qq] = f2bf(acc[i][j][qq]);
                *(us4*)((seg ? kb : qb) + (((size_t)b_ * HEADS + h) * DH + d) * NPB + nn) = pk;
            }
        }
    }
}

// ---------------- column L2 norms over tokens for q and k ----------------
__global__ __launch_bounds__(256) void colnorm_kernel(
    const ushort* __restrict__ qb, const ushort* __restrict__ kb,
    float* __restrict__ rq, float* __restrict__ rk) {
    int row = blockIdx.x;  // 0..12287 ; 6144 rows each for q,k
    const ushort* src = (row < 6144) ? (qb + (size_t)row * NPB)
                                     : (kb + (size_t)(row - 6144) * NPB);
    int tid = threadIdx.x;
    float s = 0.f;
#pragma unroll
    for (int u = 0; u < 2; u++) {
        short8 v = *(const short8*)&src[tid * 16 + u * 8];
#pragma unroll
        for (int e = 0; e < 8; e++) { float f = bf2f((ushort)v[e]); s += f * f; }
    }
#pragma unroll
    for (int off = 32; off > 0; off >>= 1) s += __shfl_down(s, off);
    __shared__ float rs[4];
    int wid = tid >> 6, lane = tid & 63;
    if (lane == 0) rs[wid] = s;
    __syncthreads();
    if (tid == 0) {
        float tot = rs[0] + rs[1] + rs[2] + rs[3];
        float inv = 1.0f / fmaxf(sqrtf(tot), 1e-12f);
        if (row < 6144) rq[row] = inv; else rk[row - 6144] = inv;
    }
}

// ---------------- attention: softmax(q^ k^T * temp), d-split across blocks -
__global__ __launch_bounds__(192) void attn_kernel(
    const ushort* __restrict__ qb, const ushort* __restrict__ kb,
    const float* __restrict__ rq, const float* __restrict__ rk,
    const float* __restrict__ temp, ushort* __restrict__ attnb) {
    int bh = blockIdx.x;
    int ds0 = blockIdx.y * 32;
    int tid = threadIdx.x;
    int wid = tid >> 6, lane = tid & 63;
    int k8 = lane >> 4, l15 = lane & 15;
    const ushort* qrow = qb + ((size_t)bh * DH + ds0) * NPB;
    const ushort* krow = kb + (size_t)bh * DH * NPB;
    f32x4 acc[2][2] = {};
    for (int n = 0; n < NPB; n += 32) {
        short8 a[2], b[2];
#pragma unroll
        for (int i = 0; i < 2; i++)
            a[i] = *(const short8*)&qrow[(size_t)(i * 16 + l15) * NPB + n + k8 * 8];
#pragma unroll
        for (int j = 0; j < 2; j++)
            b[j] = *(const short8*)&krow[(size_t)(wid * 32 + j * 16 + l15) * NPB + n + k8 * 8];
#pragma unroll
        for (int i = 0; i < 2; i++)
#pragma unroll
            for (int j = 0; j < 2; j++)
                acc[i][j] = __builtin_amdgcn_mfma_f32_16x16x32_bf16(a[i], b[j], acc[i][j], 0, 0, 0);
    }
    __shared__ float sm[32][97];
    __shared__ float red[32][16];
    float tval = temp[bh & (HEADS - 1)];
#pragma unroll
    for (int i = 0; i < 2; i++)
#pragma unroll
        for (int j = 0; j < 2; j++) {
            int e = wid * 32 + j * 16 + l15;
            float rke = rk[bh * DH + e] * tval;
#pragma unroll
            for (int qq = 0; qq < 4; qq++) {
                int d = i * 16 + k8 * 4 + qq;
                sm[d][e] = acc[i][j][qq] * rq[bh * DH + ds0 + d] * rke;
            }
        }
    __syncthreads();
    int r = tid & 31, p = tid >> 5;
    float lm = -3.4e38f;
#pragma unroll
    for (int c = 0; c < 16; c++) lm = fmaxf(lm, sm[r][p * 16 + c]);
    red[r][p] = lm;
    __syncthreads();
    float m = red[r][0];
#pragma unroll
    for (int t = 1; t < 6; t++) m = fmaxf(m, red[r][t]);
    float s = 0.f;
#pragma unroll
    for (int c = 0; c < 16; c++) {
        float ex = __expf(sm[r][p * 16 + c] - m);
        sm[r][p * 16 + c] = ex;
        s += ex;
    }
    __syncthreads();
    red[r][8 + p] = s;
    __syncthreads();
    float tot = red[r][8];
#pragma unroll
    for (int t = 1; t < 6; t++) tot += red[r][8 + t];
    float inv = 1.0f / tot;
    size_t obase = (size_t)bh * (DH * DH) + (size_t)(ds0 + r) * DH + p * 16;
#pragma unroll
    for (int c = 0; c < 16; c++)
        attnb[obase + c] = f2bf(sm[r][p * 16 + c] * inv);
}

// ---------------- PV: out_t[t][h*96+d] = sum_e attn[d,e] * v[t][h*96+e] ----
__global__ __launch_bounds__(256) void pv_kernel(
    const ushort* __restrict__ attnb, const ushort* __restrict__ vb,
    ushort* __restrict__ outt) {
    int tt = blockIdx.x;   // 0..31 token tiles of 128 (within batch)
    int bh = blockIdx.y;   // 0..63
    int b_ = bh >> 3, h = bh & 7;
    int tid = threadIdx.x;
    int wid = tid >> 6, lane = tid & 63;
    int k8 = lane >> 4, l15 = lane & 15;
    int t0 = b_ * NPB + tt * 128;
    const ushort* A = vb + (size_t)t0 * DIMC + h * DH;
    const ushort* Bm = attnb + (size_t)bh * (DH * DH);
    f32x4 acc[2][6] = {};
#pragma unroll
    for (int kk = 0; kk < DH; kk += 32) {
        short8 a[2];
#pragma unroll
        for (int i = 0; i < 2; i++)
            a[i] = *(const short8*)&A[(size_t)(wid * 32 + i * 16 + l15) * DIMC + kk + k8 * 8];
#pragma unroll
        for (int j = 0; j < 6; j++) {
            short8 bfr = *(const short8*)&Bm[(j * 16 + l15) * DH + kk + k8 * 8];
#pragma unroll
            for (int i = 0; i < 2; i++)
                acc[i][j] = __builtin_amdgcn_mfma_f32_16x16x32_bf16(a[i], bfr, acc[i][j], 0, 0, 0);
        }
    }
#pragma unroll
    for (int i = 0; i < 2; i++)
#pragma unroll
        for (int j = 0; j < 6; j++) {
            int d = j * 16 + l15;
#pragma unroll
            for (int qq = 0; qq < 4; qq++) {
                int t = t0 + wid * 32 + i * 16 + k8 * 4 + qq;
                outt[(size_t)t * DIMC + h * DH + d] = f2bf(acc[i][j][qq]);
            }
        }
}

// ---------------- proj GEMM 128x128 + bias + gamma1 + residual -------------
__global__ __launch_bounds__(256) void gemm_proj_kernel(
    const ushort* __restrict__ outt, const ushort* __restrict__ pwb,
    const float* __restrict__ pb, const float* __restrict__ g1,
    const float* __restrict__ x, float* __restrict__ out) {
    __shared__ __align__(16) ushort As[128 * 32];
    __shared__ __align__(16) ushort Bs[128 * 32];
    int orig = blockIdx.x;                  // 0..1535
    int wg = (orig & 7) * 192 + (orig >> 3);
    int nt = wg % 6, mt = wg / 6;
    int m0 = mt * 128, n0 = nt * 128;
    int tid = threadIdx.x;
    int wid = tid >> 6, lane = tid & 63;
    int wr = wid >> 1, wc = wid & 1;
    int k8 = lane >> 4, l15 = lane & 15;
    int srow = tid >> 2, scol = (tid & 3) * 8;
    const ushort* abase = outt + (size_t)(m0 + srow) * DIMC + scol;
    const ushort* bbase = pwb + (size_t)(n0 + srow) * DIMC + scol;
    f32x4 acc[4][4] = {};
    for (int kk = 0; kk < DIMC; kk += 32) {
        __syncthreads();
#pragma unroll
        for (int it = 0; it < 2; it++) {
            gload_lds16(abase + kk + (size_t)it * 64 * DIMC, &As[it * 2048 + tid * 8]);
            gload_lds16(bbase + kk + (size_t)it * 64 * DIMC, &Bs[it * 2048 + tid * 8]);
        }
        __syncthreads();
        short8 af[4], bfv[4];
#pragma unroll
        for (int i = 0; i < 4; i++)
            af[i] = *(const short8*)&As[(wr * 64 + i * 16 + l15) * 32 + k8 * 8];
#pragma unroll
        for (int j = 0; j < 4; j++)
            bfv[j] = *(const short8*)&Bs[(wc * 64 + j * 16 + l15) * 32 + k8 * 8];
#pragma unroll
        for (int i = 0; i < 4; i++)
#pragma unroll
            for (int j = 0; j < 4; j++)
                acc[i][j] = __builtin_amdgcn_mfma_f32_16x16x32_bf16(af[i], bfv[j], acc[i][j], 0, 0, 0);
    }
#pragma unroll
    for (int i = 0; i < 4; i++)
#pragma unroll
        for (int j = 0; j < 4; j++) {
            int o = n0 + wc * 64 + j * 16 + l15;
            float pbo = pb[o], g1o = g1[o];
#pragma unroll
            for (int qq = 0; qq < 4; qq++) {
                int r = m0 + wr * 64 + i * 16 + k8 * 4 + qq;
                size_t idx = (size_t)r * DIMC + o;
                out[idx] = g1o * (acc[i][j][qq] + pbo) + x[idx];
            }
        }
}

extern "C" void kernel_launch(void* const* d_in, const int* in_sizes, int n_in,
                              void* d_out, int out_size, void* d_ws, size_t ws_size,
                              hipStream_t stream) {
    const float* x     = (const float*)d_in[0];
    const float* qkvw  = (const float*)d_in[1];
    const float* projw = (const float*)d_in[2];
    const float* projb = (const float*)d_in[3];
    const float* lng   = (const float*)d_in[4];
    const float* lnb   = (const float*)d_in[5];
    const float* temp  = (const float*)d_in[6];
    const float* g1    = (const float*)d_in[7];
    float* out = (float*)d_out;

    char* w = (char*)d_ws;
    ushort* qb    = (ushort*)(w + 0);            // 50,331,648  [B,H,dh,N]
    ushort* kb    = (ushort*)(w + 50331648);     // 50,331,648
    ushort* vb    = (ushort*)(w + 100663296);    // 50,331,648  [T, C] token-major
    ushort* qwb   = (ushort*)(w + 150994944);    // 3,538,944  (dead after qkv)
    ushort* pwb   = (ushort*)(w + 154533888);    // 1,179,648
    float*  rq    = (float*)(w + 155713536);     // 24,576
    float*  rk    = (float*)(w + 155738112);     // 24,576  -> total 155,762,688
    ushort* attnb = qwb;                         // aliases qwb (dead by then)
    ushort* outt  = qb;                          // reuse q slot after attn
    // xb (bf16 LN output, 50 MB) lives in d_out's first half; proj overwrites
    // d_out completely afterwards.
    ushort* xb    = (ushort*)d_out;

    hipLaunchKernelGGL(prep_w_kernel, dim3(1728), dim3(256), 0, stream,
                       qkvw, projw, qwb, pwb);
    hipLaunchKernelGGL(ln_cvt_kernel, dim3(8192), dim3(256), 0, stream,
                       x, lng, lnb, xb);
    hipLaunchKernelGGL(gemm_qkv_kernel, dim3(4608), dim3(256), 0, stream,
                       xb, qwb, qb, kb, vb);
    hipLaunchKernelGGL(colnorm_kernel, dim3(12288), dim3(256), 0, stream, qb, kb, rq, rk);
    hipLaunchKernelGGL(attn_kernel, dim3(64, 3), dim3(192), 0, stream,
                       qb, kb, rq, rk, temp, attnb);
    hipLaunchKernelGGL(pv_kernel, dim3(32, 64), dim3(256), 0, stream, attnb, vb, outt);
    hipLaunchKernelGGL(gemm_proj_kernel, dim3(1536), dim3(256), 0, stream,
                       outt, pwb, projb, g1, x, out);
}

// Round 5
// 376.122 us; speedup vs baseline: 2.2985x; 1.0737x over previous
//
#include <hip/hip_runtime.h>
#include <hip/hip_bf16.h>
#include <stdint.h>

typedef __attribute__((ext_vector_type(8))) short short8;
typedef __attribute__((ext_vector_type(4))) float f32x4;
typedef __attribute__((ext_vector_type(4))) unsigned short us4;

#define DIMC 768
#define NTOK 32768
#define NPB 4096
#define HEADS 8
#define DH 96

__device__ __forceinline__ ushort f2bf(float f) {
    union { float f; uint32_t u; } c; c.f = f;
    uint32_t u = c.u;
    u += 0x7fffu + ((u >> 16) & 1u);
    return (ushort)(u >> 16);
}
__device__ __forceinline__ float bf2f(ushort h) {
    union { uint32_t u; float f; } c; c.u = ((uint32_t)h) << 16;
    return c.f;
}

__device__ __forceinline__ void gload_lds16(const void* g, void* l) {
    __builtin_amdgcn_global_load_lds(
        (const __attribute__((address_space(1))) void*)g,
        (__attribute__((address_space(3))) void*)l, 16, 0, 0);
}

// =====================================================================
// 256x256-tile BK=32 pipelined GEMM core (8 waves / 512 threads).
// LDS: A[2 dbuf][256 rows][32 k] + B[2 dbuf][256 rows][32 k], bf16,
// 64 B rows, st_16x32 XOR swizzle (byte ^= ((byte>>9)&1)<<5).
// Schedule per K-tile t (reading buf c=t&1):
//   ph1: read B frags (4) + A frags mh0 (4); 16 MFMA            [setprio]
//   ph2: read A frags mh1 (4); lgkmcnt(0); s_barrier;
//        stage tile t+2 -> buf c (4 gload_lds); 16 MFMA;
//        vmcnt(4) (t+1's stages done, t+2's in flight); s_barrier
// Counted vmcnt: never drains to 0 in steady state.
// =====================================================================
__device__ __forceinline__ void gemm256_core(
    const char* aglob, const char* bglob, char* lds, f32x4 (&acc)[8][4]) {
    const int tid = threadIdx.x;
    const int lane = tid & 63, wid = tid >> 6;
    const int wr = wid >> 2, wc = wid & 3;
    const int k8 = lane >> 4, l15 = lane & 15;

    // stage source mapping: linear LDS dest L, pre-swizzled global source
    const int L0 = tid * 16, L1 = (512 + tid) * 16;
    const int S0 = L0 ^ (((L0 >> 9) & 1) << 5);
    const int S1 = L1 ^ (((L1 >> 9) & 1) << 5);
    const int sr0 = S0 >> 6, sc0 = S0 & 63;
    const int sr1 = S1 >> 6, sc1 = S1 & 63;

    // fragment read offsets (swizzled), constant over the K-loop
    int aoff[2][4], boff[4];
#pragma unroll
    for (int mh = 0; mh < 2; mh++)
#pragma unroll
        for (int m = 0; m < 4; m++) {
            int row = wr * 128 + mh * 64 + m * 16 + l15;
            int o = row * 64 + k8 * 16;
            aoff[mh][m] = o ^ (((o >> 9) & 1) << 5);
        }
#pragma unroll
    for (int n = 0; n < 4; n++) {
        int row = wc * 64 + n * 16 + l15;
        int o = row * 64 + k8 * 16;
        boff[n] = o ^ (((o >> 9) & 1) << 5);
    }

#define STAGE_T(kt, c) do {                                   \
        const char* ak_ = aglob + (kt) * 64;                  \
        const char* bk_ = bglob + (kt) * 64;                  \
        char* al_ = lds + (c) * 16384;                        \
        char* bl_ = lds + 32768 + (c) * 16384;                \
        gload_lds16(ak_ + sr0 * 1536 + sc0, al_ + L0);        \
        gload_lds16(ak_ + sr1 * 1536 + sc1, al_ + L1);        \
        gload_lds16(bk_ + sr0 * 1536 + sc0, bl_ + L0);        \
        gload_lds16(bk_ + sr1 * 1536 + sc1, bl_ + L1);        \
    } while (0)

    STAGE_T(0, 0);
    STAGE_T(1, 1);
    asm volatile("s_waitcnt vmcnt(4)" ::: "memory");
    asm volatile("s_barrier" ::: "memory");

#pragma unroll 2
    for (int t = 0; t < 24; ++t) {
        const int c = t & 1;
        const char* ap = lds + c * 16384;
        const char* bp = lds + 32768 + c * 16384;
        short8 af[4], bf[4];
        // ---- phase 1 ----
#pragma unroll
        for (int n = 0; n < 4; n++) bf[n] = *(const short8*)(bp + boff[n]);
#pragma unroll
        for (int m = 0; m < 4; m++) af[m] = *(const short8*)(ap + aoff[0][m]);
        __builtin_amdgcn_s_setprio(1);
#pragma unroll
        for (int m = 0; m < 4; m++)
#pragma unroll
            for (int n = 0; n < 4; n++)
                acc[m][n] = __builtin_amdgcn_mfma_f32_16x16x32_bf16(af[m], bf[n], acc[m][n], 0, 0, 0);
        __builtin_amdgcn_s_setprio(0);
        // ---- phase 2 ----
#pragma unroll
        for (int m = 0; m < 4; m++) af[m] = *(const short8*)(ap + aoff[1][m]);
        asm volatile("s_waitcnt lgkmcnt(0)" ::: "memory");   // own LDS reads drained
        asm volatile("s_barrier" ::: "memory");              // all waves drained buf c
        if (t < 22) STAGE_T(t + 2, c);                       // overwrite consumed buf c
        __builtin_amdgcn_sched_barrier(0);
        __builtin_amdgcn_s_setprio(1);
#pragma unroll
        for (int m = 0; m < 4; m++)
#pragma unroll
            for (int n = 0; n < 4; n++)
                acc[4 + m][n] = __builtin_amdgcn_mfma_f32_16x16x32_bf16(af[m], bf[n], acc[4 + m][n], 0, 0, 0);
        __builtin_amdgcn_s_setprio(0);
        if (t < 23) {
            if (t < 22) asm volatile("s_waitcnt vmcnt(4)" ::: "memory");
            else        asm volatile("s_waitcnt vmcnt(0)" ::: "memory");
            asm volatile("s_barrier" ::: "memory");
        }
    }
#undef STAGE_T
}

// ---------------- weight prep: bf16 casts, vectorized ----------------
__global__ __launch_bounds__(256) void prep_w_kernel(
    const float* __restrict__ qw, const float* __restrict__ pw,
    ushort* __restrict__ qwb, ushort* __restrict__ pwb) {
    int i4 = (blockIdx.x * 256 + threadIdx.x) * 4;
    if (i4 < 3 * DIMC * DIMC) {
        float4 w = *(const float4*)&qw[i4];
        us4 o;
        o[0] = f2bf(w.x); o[1] = f2bf(w.y); o[2] = f2bf(w.z); o[3] = f2bf(w.w);
        *(us4*)&qwb[i4] = o;
    }
    if (i4 < DIMC * DIMC) {
        float4 w = *(const float4*)&pw[i4];
        us4 o;
        o[0] = f2bf(w.x); o[1] = f2bf(w.y); o[2] = f2bf(w.z); o[3] = f2bf(w.w);
        *(us4*)&pwb[i4] = o;
    }
}

// ---------------- LayerNorm + cast: xb = bf16(ln(x)*g + b) ----------------
__global__ __launch_bounds__(256) void ln_cvt_kernel(
    const float* __restrict__ x, const float* __restrict__ g,
    const float* __restrict__ b, ushort* __restrict__ xb) {
    int t = blockIdx.x * 4 + (threadIdx.x >> 6);
    int lane = threadIdx.x & 63;
    const float* xr = x + (size_t)t * DIMC;
    float4 v[3];
    float s = 0.f, s2 = 0.f;
#pragma unroll
    for (int u = 0; u < 3; u++) {
        v[u] = *(const float4*)&xr[u * 256 + lane * 4];
        s  += v[u].x + v[u].y + v[u].z + v[u].w;
        s2 += v[u].x * v[u].x + v[u].y * v[u].y + v[u].z * v[u].z + v[u].w * v[u].w;
    }
#pragma unroll
    for (int off = 32; off > 0; off >>= 1) {
        s  += __shfl_down(s, off);
        s2 += __shfl_down(s2, off);
    }
    s = __shfl(s, 0);
    s2 = __shfl(s2, 0);
    float mean = s * (1.0f / DIMC);
    float rstd = rsqrtf(s2 * (1.0f / DIMC) - mean * mean + 1e-5f);
    ushort* xo = xb + (size_t)t * DIMC;
#pragma unroll
    for (int u = 0; u < 3; u++) {
        float4 gv = *(const float4*)&g[u * 256 + lane * 4];
        float4 bv = *(const float4*)&b[u * 256 + lane * 4];
        us4 o;
        o[0] = f2bf((v[u].x - mean) * rstd * gv.x + bv.x);
        o[1] = f2bf((v[u].y - mean) * rstd * gv.y + bv.y);
        o[2] = f2bf((v[u].z - mean) * rstd * gv.z + bv.z);
        o[3] = f2bf((v[u].w - mean) * rstd * gv.w + bv.w);
        *(us4*)&xo[u * 256 + lane * 4] = o;
    }
}

// ---------------- QKV GEMM: 256x256 pipelined, n-tiles never straddle ------
__global__ __launch_bounds__(512) void gemm_qkv_kernel(
    const ushort* __restrict__ xb, const ushort* __restrict__ wb,
    ushort* __restrict__ qb, ushort* __restrict__ kb, ushort* __restrict__ vb) {
    __shared__ __align__(16) char lds[65536];
    int orig = blockIdx.x;                   // 0..1151
    int wg = (orig & 7) * 144 + (orig >> 3);
    int nt = wg % 9, mt = wg / 9;
    int m0 = mt * 256, n0 = nt * 256;
    f32x4 acc[8][4] = {};
    gemm256_core((const char*)(xb + (size_t)m0 * DIMC),
                 (const char*)(wb + (size_t)n0 * DIMC), lds, acc);

    int tid = threadIdx.x, lane = tid & 63, wid = tid >> 6;
    int wr = wid >> 2, wc = wid & 3;
    int k8 = lane >> 4, l15 = lane & 15;
    int seg = n0 / DIMC;                     // 0=q, 1=k, 2=v (no straddle: 768=3*256)
#pragma unroll
    for (int mh = 0; mh < 2; mh++)
#pragma unroll
        for (int m = 0; m < 4; m++) {
            int r0 = m0 + wr * 128 + mh * 64 + m * 16 + k8 * 4;
            int b_ = r0 >> 12, nn = r0 & (NPB - 1);
#pragma unroll
            for (int n = 0; n < 4; n++) {
                int o = n0 + wc * 64 + n * 16 + l15;
                f32x4 a = acc[mh * 4 + m][n];
                if (seg == 2) {
                    int oL = o - 2 * DIMC;
#pragma unroll
                    for (int qq = 0; qq < 4; qq++)
                        vb[(size_t)(r0 + qq) * DIMC + oL] = f2bf(a[qq]);
                } else {
                    int oL = o - seg * DIMC;
                    int h = oL / DH, d = oL - h * DH;
                    us4 pk;
#pragma unroll
                    for (int qq = 0; qq < 4; qq++) pk[qq] = f2bf(a[qq]);
                    *(us4*)((seg ? kb : qb) +
                            ((size_t)(b_ * HEADS + h) * DH + d) * NPB + nn) = pk;
                }
            }
        }
}

// ---------------- proj GEMM: 256x256 pipelined + bias/gamma/residual -------
__global__ __launch_bounds__(512) void gemm_proj_kernel(
    const ushort* __restrict__ outt, const ushort* __restrict__ pwb,
    const float* __restrict__ pb, const float* __restrict__ g1,
    const float* __restrict__ x, float* __restrict__ out) {
    __shared__ __align__(16) char lds[65536];
    int orig = blockIdx.x;                   // 0..383
    int wg = (orig & 7) * 48 + (orig >> 3);
    int nt = wg % 3, mt = wg / 3;
    int m0 = mt * 256, n0 = nt * 256;
    f32x4 acc[8][4] = {};
    gemm256_core((const char*)(outt + (size_t)m0 * DIMC),
                 (const char*)(pwb + (size_t)n0 * DIMC), lds, acc);

    int tid = threadIdx.x, lane = tid & 63, wid = tid >> 6;
    int wr = wid >> 2, wc = wid & 3;
    int k8 = lane >> 4, l15 = lane & 15;
#pragma unroll
    for (int mh = 0; mh < 2; mh++)
#pragma unroll
        for (int m = 0; m < 4; m++) {
            int r0 = m0 + wr * 128 + mh * 64 + m * 16 + k8 * 4;
#pragma unroll
            for (int n = 0; n < 4; n++) {
                int o = n0 + wc * 64 + n * 16 + l15;
                float pbo = pb[o], g1o = g1[o];
                f32x4 a = acc[mh * 4 + m][n];
#pragma unroll
                for (int qq = 0; qq < 4; qq++) {
                    size_t idx = (size_t)(r0 + qq) * DIMC + o;
                    out[idx] = g1o * (a[qq] + pbo) + x[idx];
                }
            }
        }
}

// ---------------- column L2 norms over tokens for q and k ----------------
__global__ __launch_bounds__(256) void colnorm_kernel(
    const ushort* __restrict__ qb, const ushort* __restrict__ kb,
    float* __restrict__ rq, float* __restrict__ rk) {
    int row = blockIdx.x;  // 0..12287 ; 6144 rows each for q,k
    const ushort* src = (row < 6144) ? (qb + (size_t)row * NPB)
                                     : (kb + (size_t)(row - 6144) * NPB);
    int tid = threadIdx.x;
    float s = 0.f;
#pragma unroll
    for (int u = 0; u < 2; u++) {
        short8 v = *(const short8*)&src[tid * 16 + u * 8];
#pragma unroll
        for (int e = 0; e < 8; e++) { float f = bf2f((ushort)v[e]); s += f * f; }
    }
#pragma unroll
    for (int off = 32; off > 0; off >>= 1) s += __shfl_down(s, off);
    __shared__ float rs[4];
    int wid = tid >> 6, lane = tid & 63;
    if (lane == 0) rs[wid] = s;
    __syncthreads();
    if (tid == 0) {
        float tot = rs[0] + rs[1] + rs[2] + rs[3];
        float inv = 1.0f / fmaxf(sqrtf(tot), 1e-12f);
        if (row < 6144) rq[row] = inv; else rk[row - 6144] = inv;
    }
}

// ---------------- attention: softmax(q^ k^T * temp), d-split across blocks -
__global__ __launch_bounds__(192) void attn_kernel(
    const ushort* __restrict__ qb, const ushort* __restrict__ kb,
    const float* __restrict__ rq, const float* __restrict__ rk,
    const float* __restrict__ temp, ushort* __restrict__ attnb) {
    int bh = blockIdx.x;
    int ds0 = blockIdx.y * 32;
    int tid = threadIdx.x;
    int wid = tid >> 6, lane = tid & 63;
    int k8 = lane >> 4, l15 = lane & 15;
    const ushort* qrow = qb + ((size_t)bh * DH + ds0) * NPB;
    const ushort* krow = kb + (size_t)bh * DH * NPB;
    f32x4 acc[2][2] = {};
    for (int n = 0; n < NPB; n += 32) {
        short8 a[2], b[2];
#pragma unroll
        for (int i = 0; i < 2; i++)
            a[i] = *(const short8*)&qrow[(size_t)(i * 16 + l15) * NPB + n + k8 * 8];
#pragma unroll
        for (int j = 0; j < 2; j++)
            b[j] = *(const short8*)&krow[(size_t)(wid * 32 + j * 16 + l15) * NPB + n + k8 * 8];
#pragma unroll
        for (int i = 0; i < 2; i++)
#pragma unroll
            for (int j = 0; j < 2; j++)
                acc[i][j] = __builtin_amdgcn_mfma_f32_16x16x32_bf16(a[i], b[j], acc[i][j], 0, 0, 0);
    }
    __shared__ float sm[32][97];
    __shared__ float red[32][16];
    float tval = temp[bh & (HEADS - 1)];
#pragma unroll
    for (int i = 0; i < 2; i++)
#pragma unroll
        for (int j = 0; j < 2; j++) {
            int e = wid * 32 + j * 16 + l15;
            float rke = rk[bh * DH + e] * tval;
#pragma unroll
            for (int qq = 0; qq < 4; qq++) {
                int d = i * 16 + k8 * 4 + qq;
                sm[d][e] = acc[i][j][qq] * rq[bh * DH + ds0 + d] * rke;
            }
        }
    __syncthreads();
    int r = tid & 31, p = tid >> 5;
    float lm = -3.4e38f;
#pragma unroll
    for (int c = 0; c < 16; c++) lm = fmaxf(lm, sm[r][p * 16 + c]);
    red[r][p] = lm;
    __syncthreads();
    float m = red[r][0];
#pragma unroll
    for (int t = 1; t < 6; t++) m = fmaxf(m, red[r][t]);
    float s = 0.f;
#pragma unroll
    for (int c = 0; c < 16; c++) {
        float ex = __expf(sm[r][p * 16 + c] - m);
        sm[r][p * 16 + c] = ex;
        s += ex;
    }
    __syncthreads();
    red[r][8 + p] = s;
    __syncthreads();
    float tot = red[r][8];
#pragma unroll
    for (int t = 1; t < 6; t++) tot += red[r][8 + t];
    float inv = 1.0f / tot;
    size_t obase = (size_t)bh * (DH * DH) + (size_t)(ds0 + r) * DH + p * 16;
#pragma unroll
    for (int c = 0; c < 16; c++)
        attnb[obase + c] = f2bf(sm[r][p * 16 + c] * inv);
}

// ---------------- PV: out_t[t][h*96+d] = sum_e attn[d,e] * v[t][h*96+e] ----
__global__ __launch_bounds__(256) void pv_kernel(
    const ushort* __restrict__ attnb, const ushort* __restrict__ vb,
    ushort* __restrict__ outt) {
    int tt = blockIdx.x;   // 0..31 token tiles of 128 (within batch)
    int bh = blockIdx.y;   // 0..63
    int b_ = bh >> 3, h = bh & 7;
    int tid = threadIdx.x;
    int wid = tid >> 6, lane = tid & 63;
    int k8 = lane >> 4, l15 = lane & 15;
    int t0 = b_ * NPB + tt * 128;
    const ushort* A = vb + (size_t)t0 * DIMC + h * DH;
    const ushort* Bm = attnb + (size_t)bh * (DH * DH);
    f32x4 acc[2][6] = {};
#pragma unroll
    for (int kk = 0; kk < DH; kk += 32) {
        short8 a[2];
#pragma unroll
        for (int i = 0; i < 2; i++)
            a[i] = *(const short8*)&A[(size_t)(wid * 32 + i * 16 + l15) * DIMC + kk + k8 * 8];
#pragma unroll
        for (int j = 0; j < 6; j++) {
            short8 bfr = *(const short8*)&Bm[(j * 16 + l15) * DH + kk + k8 * 8];
#pragma unroll
            for (int i = 0; i < 2; i++)
                acc[i][j] = __builtin_amdgcn_mfma_f32_16x16x32_bf16(a[i], bfr, acc[i][j], 0, 0, 0);
        }
    }
#pragma unroll
    for (int i = 0; i < 2; i++)
#pragma unroll
        for (int j = 0; j < 6; j++) {
            int d = j * 16 + l15;
#pragma unroll
            for (int qq = 0; qq < 4; qq++) {
                int t = t0 + wid * 32 + i * 16 + k8 * 4 + qq;
                outt[(size_t)t * DIMC + h * DH + d] = f2bf(acc[i][j][qq]);
            }
        }
}

extern "C" void kernel_launch(void* const* d_in, const int* in_sizes, int n_in,
                              void* d_out, int out_size, void* d_ws, size_t ws_size,
                              hipStream_t stream) {
    const float* x     = (const float*)d_in[0];
    const float* qkvw  = (const float*)d_in[1];
    const float* projw = (const float*)d_in[2];
    const float* projb = (const float*)d_in[3];
    const float* lng   = (const float*)d_in[4];
    const float* lnb   = (const float*)d_in[5];
    const float* temp  = (const float*)d_in[6];
    const float* g1    = (const float*)d_in[7];
    float* out = (float*)d_out;

    char* w = (char*)d_ws;
    ushort* qb    = (ushort*)(w + 0);            // 50,331,648  [B,H,dh,N]
    ushort* kb    = (ushort*)(w + 50331648);     // 50,331,648
    ushort* vb    = (ushort*)(w + 100663296);    // 50,331,648  [T, C] token-major
    ushort* qwb   = (ushort*)(w + 150994944);    // 3,538,944  (dead after qkv)
    ushort* pwb   = (ushort*)(w + 154533888);    // 1,179,648
    float*  rq    = (float*)(w + 155713536);     // 24,576
    float*  rk    = (float*)(w + 155738112);     // 24,576  -> total 155,762,688
    ushort* attnb = qwb;                         // aliases qwb (dead by then)
    ushort* outt  = qb;                          // reuse q slot after attn
    ushort* xb    = (ushort*)d_out;              // LN output in d_out (overwritten by proj)

    hipLaunchKernelGGL(prep_w_kernel, dim3(1728), dim3(256), 0, stream,
                       qkvw, projw, qwb, pwb);
    hipLaunchKernelGGL(ln_cvt_kernel, dim3(8192), dim3(256), 0, stream,
                       x, lng, lnb, xb);
    hipLaunchKernelGGL(gemm_qkv_kernel, dim3(1152), dim3(512), 0, stream,
                       xb, qwb, qb, kb, vb);
    hipLaunchKernelGGL(colnorm_kernel, dim3(12288), dim3(256), 0, stream, qb, kb, rq, rk);
    hipLaunchKernelGGL(attn_kernel, dim3(64, 3), dim3(192), 0, stream,
                       qb, kb, rq, rk, temp, attnb);
    hipLaunchKernelGGL(pv_kernel, dim3(32, 64), dim3(256), 0, stream, attnb, vb, outt);
    hipLaunchKernelGGL(gemm_proj_kernel, dim3(384), dim3(512), 0, stream,
                       outt, pwb, projb, g1, x, out);
}

// Round 6
// 345.777 us; speedup vs baseline: 2.5003x; 1.0878x over previous
//
#include <hip/hip_runtime.h>
#include <hip/hip_bf16.h>
#include <stdint.h>

typedef __attribute__((ext_vector_type(8))) short short8;
typedef __attribute__((ext_vector_type(4))) float f32x4;
typedef __attribute__((ext_vector_type(4))) unsigned short us4;

#define DIMC 768
#define NTOK 32768
#define NPB 4096
#define HEADS 8
#define DH 96

__device__ __forceinline__ ushort f2bf(float f) {
    union { float f; uint32_t u; } c; c.f = f;
    uint32_t u = c.u;
    u += 0x7fffu + ((u >> 16) & 1u);
    return (ushort)(u >> 16);
}
__device__ __forceinline__ float bf2f(ushort h) {
    union { uint32_t u; float f; } c; c.u = ((uint32_t)h) << 16;
    return c.f;
}

__device__ __forceinline__ void gload_lds16(const void* g, void* l) {
    __builtin_amdgcn_global_load_lds(
        (const __attribute__((address_space(1))) void*)g,
        (__attribute__((address_space(3))) void*)l, 16, 0, 0);
}

// =====================================================================
// 256x256-tile BK=32 GEMM core, 8 waves, 4 phases per K-tile.
// LDS layout (64 KiB): A[2][256][32], B[2][256][32] bf16, 64 B rows,
// st_16x32 swizzle (byte ^= ((byte>>9)&1)<<5), linear gload_lds dest +
// pre-swizzled global source + swizzled ds_read (validated R5 scheme).
// Stage plan (race-free; each target confirmed free >=1 barrier earlier):
//   PH1(t): stage A(t+1) -> buf t^1   (A there drained pre-bar4(t-1))
//   PH3(t): stage B(t+2) -> buf t     (B there drained by bar2(t))
// vmcnt(2) at PH4 confirms A(t+1)/B(t+1) while B(t+2) stays in flight.
// lgkmcnt counted per phase; lgkm(0) pre-bar4 publishes A-region free.
// =====================================================================
__device__ __forceinline__ void gemm256_core(
    const char* aglob, const char* bglob, char* lds, f32x4 (&acc)[8][4]) {
    const int tid = threadIdx.x;
    const int lane = tid & 63, wid = tid >> 6;
    const int wr = wid >> 2, wc = wid & 3;
    const int k8 = lane >> 4, l15 = lane & 15;

    const int L0 = tid * 16, L1 = (512 + tid) * 16;
    const int S0 = L0 ^ (((L0 >> 9) & 1) << 5);
    const int S1 = L1 ^ (((L1 >> 9) & 1) << 5);
    const int sr0 = S0 >> 6, sc0 = S0 & 63;
    const int sr1 = S1 >> 6, sc1 = S1 & 63;

    int aoff[8], boff[4];
#pragma unroll
    for (int m = 0; m < 8; m++) {
        int row = wr * 128 + m * 16 + l15;
        int o = row * 64 + k8 * 16;
        aoff[m] = o ^ (((o >> 9) & 1) << 5);
    }
#pragma unroll
    for (int n = 0; n < 4; n++) {
        int row = wc * 64 + n * 16 + l15;
        int o = row * 64 + k8 * 16;
        boff[n] = o ^ (((o >> 9) & 1) << 5);
    }

#define STG_A(kt, c) do {                                     \
        const char* ak_ = aglob + (size_t)(kt) * 64;          \
        char* al_ = lds + (c) * 16384;                        \
        gload_lds16(ak_ + sr0 * 1536 + sc0, al_ + L0);        \
        gload_lds16(ak_ + sr1 * 1536 + sc1, al_ + L1);        \
    } while (0)
#define STG_B(kt, c) do {                                     \
        const char* bk_ = bglob + (size_t)(kt) * 64;          \
        char* bl_ = lds + 32768 + (c) * 16384;                \
        gload_lds16(bk_ + sr0 * 1536 + sc0, bl_ + L0);        \
        gload_lds16(bk_ + sr1 * 1536 + sc1, bl_ + L1);        \
    } while (0)
#define MFMA_PAIR(ma, mb)                                                          \
    __builtin_amdgcn_s_setprio(1);                                                 \
    _Pragma("unroll")                                                              \
    for (int n = 0; n < 4; n++)                                                    \
        acc[ma][n] = __builtin_amdgcn_mfma_f32_16x16x32_bf16(af[ma], bf[n], acc[ma][n], 0, 0, 0); \
    _Pragma("unroll")                                                              \
    for (int n = 0; n < 4; n++)                                                    \
        acc[mb][n] = __builtin_amdgcn_mfma_f32_16x16x32_bf16(af[mb], bf[n], acc[mb][n], 0, 0, 0); \
    __builtin_amdgcn_s_setprio(0);

    // prologue: tile0 both operands + B(1); A(1) comes from PH1(0)
    STG_A(0, 0); STG_B(0, 0); STG_B(1, 1);
    asm volatile("s_waitcnt vmcnt(2)" ::: "memory");   // A(0),B(0) landed; B(1) in flight
    asm volatile("s_barrier" ::: "memory");

#pragma unroll 2
    for (int t = 0; t < 24; ++t) {
        const int c = t & 1;
        const char* ap = lds + c * 16384;
        const char* bp = lds + 32768 + c * 16384;
        short8 af[8], bf[4];
        // ---- PH1 ----
#pragma unroll
        for (int n = 0; n < 4; n++) bf[n] = *(const short8*)(bp + boff[n]);
#pragma unroll
        for (int m = 0; m < 4; m++) af[m] = *(const short8*)(ap + aoff[m]);
        if (t + 1 < 24) STG_A(t + 1, c ^ 1);
        asm volatile("s_barrier" ::: "memory");
        asm volatile("s_waitcnt lgkmcnt(2)" ::: "memory");
        __builtin_amdgcn_sched_barrier(0);
        MFMA_PAIR(0, 1)
        // ---- PH2 ----
#pragma unroll
        for (int m = 4; m < 8; m++) af[m] = *(const short8*)(ap + aoff[m]);
        asm volatile("s_barrier" ::: "memory");
        asm volatile("s_waitcnt lgkmcnt(4)" ::: "memory");
        __builtin_amdgcn_sched_barrier(0);
        MFMA_PAIR(2, 3)
        // ---- PH3 ----
        if (t + 2 < 24) STG_B(t + 2, c);
        asm volatile("s_barrier" ::: "memory");
        asm volatile("s_waitcnt lgkmcnt(2)" ::: "memory");
        __builtin_amdgcn_sched_barrier(0);
        MFMA_PAIR(4, 5)
        // ---- PH4 ----
        if (t + 2 < 24) asm volatile("s_waitcnt vmcnt(2)" ::: "memory");
        else            asm volatile("s_waitcnt vmcnt(0)" ::: "memory");
        asm volatile("s_waitcnt lgkmcnt(0)" ::: "memory");  // A-region free as of next bar
        __builtin_amdgcn_sched_barrier(0);
        asm volatile("s_barrier" ::: "memory");
        MFMA_PAIR(6, 7)
    }
#undef STG_A
#undef STG_B
#undef MFMA_PAIR
}

// ---------------- weight prep: bf16 casts, vectorized ----------------
__global__ __launch_bounds__(256) void prep_w_kernel(
    const float* __restrict__ qw, const float* __restrict__ pw,
    ushort* __restrict__ qwb, ushort* __restrict__ pwb) {
    int i4 = (blockIdx.x * 256 + threadIdx.x) * 4;
    if (i4 < 3 * DIMC * DIMC) {
        float4 w = *(const float4*)&qw[i4];
        us4 o;
        o[0] = f2bf(w.x); o[1] = f2bf(w.y); o[2] = f2bf(w.z); o[3] = f2bf(w.w);
        *(us4*)&qwb[i4] = o;
    }
    if (i4 < DIMC * DIMC) {
        float4 w = *(const float4*)&pw[i4];
        us4 o;
        o[0] = f2bf(w.x); o[1] = f2bf(w.y); o[2] = f2bf(w.z); o[3] = f2bf(w.w);
        *(us4*)&pwb[i4] = o;
    }
}

// ---------------- LayerNorm + cast: xb = bf16(ln(x)*g + b) ----------------
__global__ __launch_bounds__(256) void ln_cvt_kernel(
    const float* __restrict__ x, const float* __restrict__ g,
    const float* __restrict__ b, ushort* __restrict__ xb) {
    int t = blockIdx.x * 4 + (threadIdx.x >> 6);
    int lane = threadIdx.x & 63;
    const float* xr = x + (size_t)t * DIMC;
    float4 v[3];
    float s = 0.f, s2 = 0.f;
#pragma unroll
    for (int u = 0; u < 3; u++) {
        v[u] = *(const float4*)&xr[u * 256 + lane * 4];
        s  += v[u].x + v[u].y + v[u].z + v[u].w;
        s2 += v[u].x * v[u].x + v[u].y * v[u].y + v[u].z * v[u].z + v[u].w * v[u].w;
    }
#pragma unroll
    for (int off = 32; off > 0; off >>= 1) {
        s  += __shfl_down(s, off);
        s2 += __shfl_down(s2, off);
    }
    s = __shfl(s, 0);
    s2 = __shfl(s2, 0);
    float mean = s * (1.0f / DIMC);
    float rstd = rsqrtf(s2 * (1.0f / DIMC) - mean * mean + 1e-5f);
    ushort* xo = xb + (size_t)t * DIMC;
#pragma unroll
    for (int u = 0; u < 3; u++) {
        float4 gv = *(const float4*)&g[u * 256 + lane * 4];
        float4 bv = *(const float4*)&b[u * 256 + lane * 4];
        us4 o;
        o[0] = f2bf((v[u].x - mean) * rstd * gv.x + bv.x);
        o[1] = f2bf((v[u].y - mean) * rstd * gv.y + bv.y);
        o[2] = f2bf((v[u].z - mean) * rstd * gv.z + bv.z);
        o[3] = f2bf((v[u].w - mean) * rstd * gv.w + bv.w);
        *(us4*)&xo[u * 256 + lane * 4] = o;
    }
}

// ---------------- QKV GEMM: 256x256 4-phase pipelined ----------------
__global__ __launch_bounds__(512) void gemm_qkv_kernel(
    const ushort* __restrict__ xb, const ushort* __restrict__ wb,
    ushort* __restrict__ qb, ushort* __restrict__ kb, ushort* __restrict__ vb) {
    __shared__ __align__(16) char lds[65536];
    int orig = blockIdx.x;                   // 0..1151
    int wg = (orig & 7) * 144 + (orig >> 3);
    int nt = wg % 9, mt = wg / 9;
    int m0 = mt * 256, n0 = nt * 256;
    f32x4 acc[8][4] = {};
    gemm256_core((const char*)(xb + (size_t)m0 * DIMC),
                 (const char*)(wb + (size_t)n0 * DIMC), lds, acc);

    int tid = threadIdx.x, lane = tid & 63, wid = tid >> 6;
    int wr = wid >> 2, wc = wid & 3;
    int k8 = lane >> 4, l15 = lane & 15;
    int seg = n0 / DIMC;                     // 0=q, 1=k, 2=v (no straddle)
#pragma unroll
    for (int m8 = 0; m8 < 8; m8++) {
        int r0 = m0 + wr * 128 + m8 * 16 + k8 * 4;
        int b_ = r0 >> 12, nn = r0 & (NPB - 1);
#pragma unroll
        for (int n = 0; n < 4; n++) {
            int o = n0 + wc * 64 + n * 16 + l15;
            f32x4 a = acc[m8][n];
            if (seg == 2) {
                int oL = o - 2 * DIMC;
#pragma unroll
                for (int qq = 0; qq < 4; qq++)
                    vb[(size_t)(r0 + qq) * DIMC + oL] = f2bf(a[qq]);
            } else {
                int oL = o - seg * DIMC;
                int h = oL / DH, d = oL - h * DH;
                us4 pk;
#pragma unroll
                for (int qq = 0; qq < 4; qq++) pk[qq] = f2bf(a[qq]);
                *(us4*)((seg ? kb : qb) +
                        ((size_t)(b_ * HEADS + h) * DH + d) * NPB + nn) = pk;
            }
        }
    }
}

// ---------------- proj GEMM: 256x256 4-phase + bias/gamma/residual ---------
__global__ __launch_bounds__(512) void gemm_proj_kernel(
    const ushort* __restrict__ outt, const ushort* __restrict__ pwb,
    const float* __restrict__ pb, const float* __restrict__ g1,
    const float* __restrict__ x, float* __restrict__ out) {
    __shared__ __align__(16) char lds[65536];
    int orig = blockIdx.x;                   // 0..383
    int wg = (orig & 7) * 48 + (orig >> 3);
    int nt = wg % 3, mt = wg / 3;
    int m0 = mt * 256, n0 = nt * 256;
    f32x4 acc[8][4] = {};
    gemm256_core((const char*)(outt + (size_t)m0 * DIMC),
                 (const char*)(pwb + (size_t)n0 * DIMC), lds, acc);

    int tid = threadIdx.x, lane = tid & 63, wid = tid >> 6;
    int wr = wid >> 2, wc = wid & 3;
    int k8 = lane >> 4, l15 = lane & 15;
#pragma unroll
    for (int m8 = 0; m8 < 8; m8++) {
        int r0 = m0 + wr * 128 + m8 * 16 + k8 * 4;
#pragma unroll
        for (int n = 0; n < 4; n++) {
            int o = n0 + wc * 64 + n * 16 + l15;
            float pbo = pb[o], g1o = g1[o];
            f32x4 a = acc[m8][n];
#pragma unroll
            for (int qq = 0; qq < 4; qq++) {
                size_t idx = (size_t)(r0 + qq) * DIMC + o;
                out[idx] = g1o * (a[qq] + pbo) + x[idx];
            }
        }
    }
}

// ---------------- column L2 norms over tokens for q and k ----------------
__global__ __launch_bounds__(256) void colnorm_kernel(
    const ushort* __restrict__ qb, const ushort* __restrict__ kb,
    float* __restrict__ rq, float* __restrict__ rk) {
    int row = blockIdx.x;  // 0..12287 ; 6144 rows each for q,k
    const ushort* src = (row < 6144) ? (qb + (size_t)row * NPB)
                                     : (kb + (size_t)(row - 6144) * NPB);
    int tid = threadIdx.x;
    float s = 0.f;
#pragma unroll
    for (int u = 0; u < 2; u++) {
        short8 v = *(const short8*)&src[tid * 16 + u * 8];
#pragma unroll
        for (int e = 0; e < 8; e++) { float f = bf2f((ushort)v[e]); s += f * f; }
    }
#pragma unroll
    for (int off = 32; off > 0; off >>= 1) s += __shfl_down(s, off);
    __shared__ float rs[4];
    int wid = tid >> 6, lane = tid & 63;
    if (lane == 0) rs[wid] = s;
    __syncthreads();
    if (tid == 0) {
        float tot = rs[0] + rs[1] + rs[2] + rs[3];
        float inv = 1.0f / fmaxf(sqrtf(tot), 1e-12f);
        if (row < 6144) rq[row] = inv; else rk[row - 6144] = inv;
    }
}

// ---------------- attn partial: S[ch][bh][96][96] = q·k^T over n-chunk -----
// grid (64, 8), 9 waves; each q/k element read exactly once across the grid
__global__ __launch_bounds__(576) void attn_qk_kernel(
    const ushort* __restrict__ qb, const ushort* __restrict__ kb,
    float* __restrict__ S) {
    int bh = blockIdx.x, ch = blockIdx.y;
    int tid = threadIdx.x, wid = tid >> 6, lane = tid & 63;
    int wr = wid / 3, wc = wid - wr * 3;
    int k8 = lane >> 4, l15 = lane & 15;
    const ushort* qrow = qb + (size_t)bh * DH * NPB + ch * 512;
    const ushort* krow = kb + (size_t)bh * DH * NPB + ch * 512;
    f32x4 acc[2][2] = {};
    for (int n = 0; n < 512; n += 32) {
        short8 a[2], b[2];
#pragma unroll
        for (int i = 0; i < 2; i++)
            a[i] = *(const short8*)&qrow[(size_t)(wr * 32 + i * 16 + l15) * NPB + n + k8 * 8];
#pragma unroll
        for (int j = 0; j < 2; j++)
            b[j] = *(const short8*)&krow[(size_t)(wc * 32 + j * 16 + l15) * NPB + n + k8 * 8];
#pragma unroll
        for (int i = 0; i < 2; i++)
#pragma unroll
            for (int j = 0; j < 2; j++)
                acc[i][j] = __builtin_amdgcn_mfma_f32_16x16x32_bf16(a[i], b[j], acc[i][j], 0, 0, 0);
    }
    float* So = S + ((size_t)ch * 64 + bh) * (DH * DH);
#pragma unroll
    for (int i = 0; i < 2; i++)
#pragma unroll
        for (int j = 0; j < 2; j++) {
            int e = wc * 32 + j * 16 + l15;
#pragma unroll
            for (int qq = 0; qq < 4; qq++) {
                int d = wr * 32 + i * 16 + k8 * 4 + qq;
                So[d * DH + e] = acc[i][j][qq];
            }
        }
}

// ---------------- attn softmax: sum chunks, scale, softmax, store bf16 -----
// grid (64, 3), 192 threads: 32 rows x 6 col-groups of 16
__global__ __launch_bounds__(192) void attn_soft_kernel(
    const float* __restrict__ S, const float* __restrict__ rq,
    const float* __restrict__ rk, const float* __restrict__ temp,
    ushort* __restrict__ attnb) {
    int bh = blockIdx.x, ds0 = blockIdx.y * 32;
    int tid = threadIdx.x, r = tid & 31, p = tid >> 5;
    int d = ds0 + r;
    float4 v[4] = {};
#pragma unroll 1
    for (int ch = 0; ch < 8; ch++) {
        const float* So = S + (((size_t)ch * 64 + bh) * DH + d) * DH + p * 16;
#pragma unroll
        for (int u = 0; u < 4; u++) {
            float4 w = *(const float4*)&So[u * 4];
            v[u].x += w.x; v[u].y += w.y; v[u].z += w.z; v[u].w += w.w;
        }
    }
    float sd = rq[bh * DH + d] * temp[bh & (HEADS - 1)];
#pragma unroll
    for (int u = 0; u < 4; u++) {
        float4 rk4 = *(const float4*)&rk[bh * DH + p * 16 + u * 4];
        v[u].x *= sd * rk4.x; v[u].y *= sd * rk4.y;
        v[u].z *= sd * rk4.z; v[u].w *= sd * rk4.w;
    }
    __shared__ float red[32][8], red2[32][8];
    float lm = -3.4e38f;
#pragma unroll
    for (int u = 0; u < 4; u++)
        lm = fmaxf(lm, fmaxf(fmaxf(v[u].x, v[u].y), fmaxf(v[u].z, v[u].w)));
    red[r][p] = lm;
    __syncthreads();
    float m = red[r][0];
#pragma unroll
    for (int u = 1; u < 6; u++) m = fmaxf(m, red[r][u]);
    float s = 0.f;
#pragma unroll
    for (int u = 0; u < 4; u++) {
        v[u].x = __expf(v[u].x - m); v[u].y = __expf(v[u].y - m);
        v[u].z = __expf(v[u].z - m); v[u].w = __expf(v[u].w - m);
        s += v[u].x + v[u].y + v[u].z + v[u].w;
    }
    red2[r][p] = s;
    __syncthreads();
    float tot = red2[r][0];
#pragma unroll
    for (int u = 1; u < 6; u++) tot += red2[r][u];
    float inv = 1.0f / tot;
    ushort* ao = attnb + (size_t)bh * (DH * DH) + (size_t)d * DH + p * 16;
#pragma unroll
    for (int u = 0; u < 4; u++) {
        us4 pk;
        pk[0] = f2bf(v[u].x * inv); pk[1] = f2bf(v[u].y * inv);
        pk[2] = f2bf(v[u].z * inv); pk[3] = f2bf(v[u].w * inv);
        *(us4*)&ao[u * 4] = pk;
    }
}

// ---------------- PV: out_t[t][h*96+d] = sum_e attn[d,e] * v[t][h*96+e] ----
__global__ __launch_bounds__(256) void pv_kernel(
    const ushort* __restrict__ attnb, const ushort* __restrict__ vb,
    ushort* __restrict__ outt) {
    int tt = blockIdx.x;   // 0..31 token tiles of 128 (within batch)
    int bh = blockIdx.y;   // 0..63
    int b_ = bh >> 3, h = bh & 7;
    int tid = threadIdx.x;
    int wid = tid >> 6, lane = tid & 63;
    int k8 = lane >> 4, l15 = lane & 15;
    int t0 = b_ * NPB + tt * 128;
    const ushort* A = vb + (size_t)t0 * DIMC + h * DH;
    const ushort* Bm = attnb + (size_t)bh * (DH * DH);
    f32x4 acc[2][6] = {};
#pragma unroll
    for (int kk = 0; kk < DH; kk += 32) {
        short8 a[2];
#pragma unroll
        for (int i = 0; i < 2; i++)
            a[i] = *(const short8*)&A[(size_t)(wid * 32 + i * 16 + l15) * DIMC + kk + k8 * 8];
#pragma unroll
        for (int j = 0; j < 6; j++) {
            short8 bfr = *(const short8*)&Bm[(j * 16 + l15) * DH + kk + k8 * 8];
#pragma unroll
            for (int i = 0; i < 2; i++)
                acc[i][j] = __builtin_amdgcn_mfma_f32_16x16x32_bf16(a[i], bfr, acc[i][j], 0, 0, 0);
        }
    }
#pragma unroll
    for (int i = 0; i < 2; i++)
#pragma unroll
        for (int j = 0; j < 6; j++) {
            int d = j * 16 + l15;
#pragma unroll
            for (int qq = 0; qq < 4; qq++) {
                int t = t0 + wid * 32 + i * 16 + k8 * 4 + qq;
                outt[(size_t)t * DIMC + h * DH + d] = f2bf(acc[i][j][qq]);
            }
        }
}

extern "C" void kernel_launch(void* const* d_in, const int* in_sizes, int n_in,
                              void* d_out, int out_size, void* d_ws, size_t ws_size,
                              hipStream_t stream) {
    const float* x     = (const float*)d_in[0];
    const float* qkvw  = (const float*)d_in[1];
    const float* projw = (const float*)d_in[2];
    const float* projb = (const float*)d_in[3];
    const float* lng   = (const float*)d_in[4];
    const float* lnb   = (const float*)d_in[5];
    const float* temp  = (const float*)d_in[6];
    const float* g1    = (const float*)d_in[7];
    float* out = (float*)d_out;

    char* w = (char*)d_ws;
    ushort* qb    = (ushort*)(w + 0);            // 50,331,648  [B,H,dh,N]
    ushort* kb    = (ushort*)(w + 50331648);     // 50,331,648
    ushort* vb    = (ushort*)(w + 100663296);    // 50,331,648  [T, C] token-major
    ushort* qwb   = (ushort*)(w + 150994944);    // 3,538,944  (dead after qkv)
    ushort* pwb   = (ushort*)(w + 154533888);    // 1,179,648
    float*  rq    = (float*)(w + 155713536);     // 24,576
    float*  rk    = (float*)(w + 155738112);     // 24,576  -> total 155,762,688
    ushort* attnb = qwb;                         // aliases qwb (dead by then)
    ushort* outt  = qb;                          // reuse q slot after attn
    ushort* xb    = (ushort*)d_out;              // LN output (overwritten by proj)
    float*  S     = (float*)((char*)d_out + 50331648);  // 18,874,368 attn partials

    hipLaunchKernelGGL(prep_w_kernel, dim3(1728), dim3(256), 0, stream,
                       qkvw, projw, qwb, pwb);
    hipLaunchKernelGGL(ln_cvt_kernel, dim3(8192), dim3(256), 0, stream,
                       x, lng, lnb, xb);
    hipLaunchKernelGGL(gemm_qkv_kernel, dim3(1152), dim3(512), 0, stream,
                       xb, qwb, qb, kb, vb);
    hipLaunchKernelGGL(colnorm_kernel, dim3(12288), dim3(256), 0, stream, qb, kb, rq, rk);
    hipLaunchKernelGGL(attn_qk_kernel, dim3(64, 8), dim3(576), 0, stream, qb, kb, S);
    hipLaunchKernelGGL(attn_soft_kernel, dim3(64, 3), dim3(192), 0, stream,
                       S, rq, rk, temp, attnb);
    hipLaunchKernelGGL(pv_kernel, dim3(32, 64), dim3(256), 0, stream, attnb, vb, outt);
    hipLaunchKernelGGL(gemm_proj_kernel, dim3(384), dim3(512), 0, stream,
                       outt, pwb, projb, g1, x, out);
}